// Round 13
// baseline (180.959 us; speedup 1.0000x reference)
//
#include <hip/hip_runtime.h>

// Problem constants
#define Bn 2
#define Cn 256
#define Nn 4096
#define SPLIT 4
#define KVB 32
#define NSTEP ((Nn / SPLIT) / KVB)

typedef __attribute__((ext_vector_type(8))) short short8;
typedef __attribute__((ext_vector_type(4))) float f32x4;

__device__ __forceinline__ unsigned short f2bf(float f) {
  union { float f; unsigned int u; } v; v.f = f;
  unsigned int r = (v.u + 0x7FFFu + ((v.u >> 16) & 1u)) >> 16;
  return (unsigned short)r;
}

__device__ __forceinline__ f32x4 mfma16(short8 a, short8 b, f32x4 c) {
  return __builtin_amdgcn_mfma_f32_16x16x32_bf16(a, b, c, 0, 0, 0);
}

// ---------------------------------------------------------------------------
// 1) Transpose conv weights [co][ci][t] -> bf16 w2[tensor][t][co][ci]
// ---------------------------------------------------------------------------
__global__ void prep_w_kernel(const float* __restrict__ wq,
                              const float* __restrict__ wk,
                              const float* __restrict__ wv,
                              unsigned short* __restrict__ w2) {
  int idx = blockIdx.x * 256 + threadIdx.x;           // 3*3*256*256 = 589824
  int tensor = idx / 196608;
  int rem = idx % 196608;
  int t  = rem >> 16;
  int co = (rem >> 8) & 255;
  int ci = rem & 255;
  const float* w = (tensor == 0) ? wq : (tensor == 1) ? wk : wv;
  w2[idx] = f2bf(w[(co * 256 + ci) * 3 + t]);
}

// ---------------------------------------------------------------------------
// 2) Gated channel-split 1x1x1 convs + SiLU.  fp32 (feeds output directly).
//    Writes xg fp32 [b][c][n] and xgT bf16 [b][n][c].
// ---------------------------------------------------------------------------
__global__ __launch_bounds__(256) void gated_kernel(
    const float* __restrict__ x,
    const float* __restrict__ w1, const float* __restrict__ b1,
    const float* __restrict__ w2, const float* __restrict__ b2,
    const float* __restrict__ w3, const float* __restrict__ b3,
    const float* __restrict__ w4, const float* __restrict__ b4,
    float* __restrict__ xg, unsigned short* __restrict__ xgT) {
  __shared__ float Wl[64][65];
  __shared__ float Xl[64][65];
  __shared__ unsigned short Yl[64][72];
  const int tid = threadIdx.x;
  const int n0 = blockIdx.x * 64;
  const int q  = blockIdx.y;
  const int b  = blockIdx.z;
  const float* wsel = (q == 0) ? w1 : (q == 1) ? w2 : (q == 2) ? w3 : w4;
  const float* bsel = (q == 0) ? b1 : (q == 1) ? b2 : (q == 2) ? b3 : b4;

  #pragma unroll
  for (int it = 0; it < 4; it++) {
    int i = (tid + it * 256) * 4;
    float4 v = *(const float4*)(wsel + i);
    int co = i >> 6, ci = i & 63;
    Wl[co][ci] = v.x; Wl[co][ci + 1] = v.y; Wl[co][ci + 2] = v.z; Wl[co][ci + 3] = v.w;
  }
  {
    int ci = tid >> 2, part = tid & 3;
    const float* src = x + ((size_t)(b * Cn + q * 64 + ci)) * Nn + n0 + part * 16;
    #pragma unroll
    for (int j = 0; j < 4; j++) {
      float4 v = ((const float4*)src)[j];
      float* dst = &Xl[ci][part * 16 + j * 4];
      dst[0] = v.x; dst[1] = v.y; dst[2] = v.z; dst[3] = v.w;
    }
  }
  __syncthreads();
  const int co = tid >> 2, npart = tid & 3;
  float acc[16];
  {
    float bias = bsel[co];
    #pragma unroll
    for (int j = 0; j < 16; j++) acc[j] = bias;
  }
  for (int ci = 0; ci < 64; ci++) {
    float wv_ = Wl[co][ci];
    const float* xr = &Xl[ci][npart * 16];
    #pragma unroll
    for (int j = 0; j < 16; j++) acc[j] += wv_ * xr[j];
  }
  float* xgp = xg + ((size_t)(b * Cn + q * 64 + co)) * Nn + n0 + npart * 16;
  #pragma unroll
  for (int j = 0; j < 16; j++) {
    float v = acc[j];
    float s = v / (1.f + __expf(-v));   // SiLU
    xgp[j] = s;
    Yl[npart * 16 + j][co] = f2bf(s);
  }
  __syncthreads();
  { // transpose-out: 4 threads per row, 16 channels each -> full 64x64 tile
    int r = tid >> 2, cp = tid & 3;
    union { unsigned short u[16]; uint4 v[2]; } pk;
    #pragma unroll
    for (int j = 0; j < 16; j++) pk.u[j] = Yl[r][cp * 16 + j];
    uint4* dst = (uint4*)(xgT + ((size_t)(b * Nn + n0 + r)) * Cn + q * 64 + cp * 16);
    dst[0] = pk.v[0];
    dst[1] = pk.v[1];
  }
}

// ---------------------------------------------------------------------------
// 3) QKV directional convs + fused channel LayerNorm.
// ---------------------------------------------------------------------------
__global__ __launch_bounds__(256) void qkvconv_ln_kernel(
    const unsigned short* __restrict__ xgT, const unsigned short* __restrict__ w2,
    const float* __restrict__ bq, const float* __restrict__ bk,
    const float* __restrict__ bv,
    const float* __restrict__ qs, const float* __restrict__ qb,
    const float* __restrict__ ks, const float* __restrict__ kb,
    const float* __restrict__ vs, const float* __restrict__ vb,
    unsigned short* __restrict__ qkv) {
  __shared__ unsigned short Al[64 * 32];    // swizzled: chunk ^= row&3
  __shared__ unsigned short Bl[256 * 32];   // swizzled: chunk ^= row&3
  const int tid = threadIdx.x;
  const int lane = tid & 63, wave = tid >> 6;
  const int l15 = lane & 15, l4 = lane >> 4;
  const int n0  = blockIdx.x * 64;
  const int b = blockIdx.y;
  const int tensor = blockIdx.z;
  const int cstride = (tensor == 0) ? 16 : (tensor == 1) ? 1 : 256;   // H, W, D
  const float* bias = (tensor == 0) ? bq : (tensor == 1) ? bk : bv;
  const float* lsc = (tensor == 0) ? qs : (tensor == 1) ? ks : vs;
  const float* lbi = (tensor == 0) ? qb : (tensor == 1) ? kb : vb;
  const unsigned short* wbase = w2 + (size_t)tensor * 196608;
  const unsigned short* xbase = xgT + (size_t)b * Nn * Cn;

  f32x4 acc[16];
  #pragma unroll
  for (int i = 0; i < 16; i++) acc[i] = (f32x4){0.f, 0.f, 0.f, 0.f};

  const int arow = tid >> 2, akp = tid & 3;     // A staging assignment
  const int n = n0 + arow;
  const int coordv = (n / cstride) & 15;        // coordinate along conv axis

  for (int kc = 0; kc < 24; kc++) {
    int t = kc >> 3;
    int cib = (kc & 7) * 32;
    int shift = t - 1;
    int c2 = coordv + shift;
    { // A: 64 rows x 32ch, 1 chunk/thread, swizzled
      const unsigned short* asrc =
          xbase + ((size_t)(n + shift * cstride)) * Cn + cib + akp * 8;
      uint4 av = (c2 >= 0 && c2 < 16) ? *(const uint4*)asrc : (uint4){0, 0, 0, 0};
      *(uint4*)(Al + arow * 32 + ((akp ^ (arow & 3)) * 8)) = av;
    }
    { // B: 256 rows x 32ch, 4 chunks/thread (rows tid>>2 + 64i), swizzled
      #pragma unroll
      for (int i = 0; i < 4; i++) {
        int row = (tid >> 2) + 64 * i;
        int chunk = tid & 3;
        const unsigned short* bsrc =
            wbase + ((size_t)(t * 256 + row)) * 256 + cib + chunk * 8;
        *(uint4*)(Bl + row * 32 + ((chunk ^ (row & 3)) * 8)) = *(const uint4*)bsrc;
      }
    }
    __syncthreads();
    int arowf = wave * 16 + l15;
    short8 af = *(const short8*)(Al + arowf * 32 + ((l4 ^ (arowf & 3)) * 8));
    #pragma unroll
    for (int ct = 0; ct < 16; ct++) {
      int brow = ct * 16 + l15;
      short8 bf = *(const short8*)(Bl + brow * 32 + ((l4 ^ (brow & 3)) * 8));
      acc[ct] = mfma16(af, bf, acc[ct]);
    }
    __syncthreads();
  }

  // bias + channel-LN per row (rows r = l4*4+i, cols ct*16+l15)
  float bv_[16], scv[16], lbv[16];
  #pragma unroll
  for (int ct = 0; ct < 16; ct++) {
    int c = ct * 16 + l15;
    bv_[ct] = bias[c]; scv[ct] = lsc[c]; lbv[ct] = lbi[c];
  }
  unsigned short* ob = qkv + ((size_t)(tensor * Bn + b) * Nn) * Cn;
  #pragma unroll
  for (int i = 0; i < 4; i++) {
    float s = 0.f, s2 = 0.f;
    #pragma unroll
    for (int ct = 0; ct < 16; ct++) {
      float v = acc[ct][i] + bv_[ct];
      s += v; s2 += v * v;
    }
    s  += __shfl_xor(s, 1);  s  += __shfl_xor(s, 2);
    s  += __shfl_xor(s, 4);  s  += __shfl_xor(s, 8);
    s2 += __shfl_xor(s2, 1); s2 += __shfl_xor(s2, 2);
    s2 += __shfl_xor(s2, 4); s2 += __shfl_xor(s2, 8);
    float mean = s * (1.f / 256.f);
    float var  = s2 * (1.f / 256.f) - mean * mean;
    float inv  = rsqrtf(var + 1e-5f);
    int nn = n0 + wave * 16 + l4 * 4 + i;
    unsigned short* orow = ob + (size_t)nn * Cn;
    #pragma unroll
    for (int ct = 0; ct < 16; ct++) {
      float v = acc[ct][i] + bv_[ct];
      orow[ct * 16 + l15] = f2bf((v - mean) * inv * scv[ct] + lbv[ct]);
    }
  }
}

// ---------------------------------------------------------------------------
// 5) Flash attention partials — R2 configuration (grid dim3(64,2,4), 256 thr,
//    Q-tile 64, KVB=32, Ks[32][264]/Vt[256][40]/Pl[4][16][40], float Opart)
//    with ONE change: register prefetch. Loads for step t+1 issue right after
//    barrier 1 and fly under step t's compute; the LDS write at t+1's loop
//    top then doesn't wait on memory. Staging maps identical to R2.
// ---------------------------------------------------------------------------
__global__ __launch_bounds__(256, 2) void flash_kernel(
    const unsigned short* __restrict__ qkv, float* __restrict__ Opart,
    float* __restrict__ ml) {
  __shared__ unsigned short Ks[KVB][264];    // row-major K tile (pad 8)
  __shared__ unsigned short Vt[256][40];     // V transposed [c][k] (pad 8)
  __shared__ unsigned short Pl[4][16][40];   // per-wave P tile
  const int tid = threadIdx.x, lane = tid & 63, wave = tid >> 6;
  const int l15 = lane & 15, l4 = lane >> 4;
  const int qt = blockIdx.x, b = blockIdx.y, sp = blockIdx.z;
  const unsigned short* Q = qkv + (size_t)(0 * Bn + b) * Nn * Cn;
  const unsigned short* K = qkv + (size_t)(1 * Bn + b) * Nn * Cn;
  const unsigned short* V = qkv + (size_t)(2 * Bn + b) * Nn * Cn;
  const int q0 = qt * 64 + wave * 16;

  short8 qf[8];
  {
    const unsigned short* qp = Q + (size_t)(q0 + l15) * Cn + l4 * 8;
    #pragma unroll
    for (int kk = 0; kk < 8; kk++) qf[kk] = *(const short8*)(qp + kk * 32);
  }
  f32x4 acc_o[16];
  #pragma unroll
  for (int i = 0; i < 16; i++) acc_o[i] = (f32x4){0.f, 0.f, 0.f, 0.f};
  float m_r[4], l_r[4];
  #pragma unroll
  for (int i = 0; i < 4; i++) { m_r[i] = -1e30f; l_r[i] = 0.f; }

  const int kvbase = sp * (Nn / SPLIT);
  const float scl = 0.0625f;                  // 1/sqrt(256)

  // staging maps — identical to R2
  const int kr = tid >> 3, kcp = tid & 7;            // K: row, 64B base
  const int vrp = (tid & 15) * 2, vch = (tid >> 4) * 16;  // V: 2 rows x 16 ch

  uint4 ka[4], va[4];
  { // prologue prefetch (step 0) — same addresses as R2's loop-top loads
    const unsigned short* src = K + (size_t)(kvbase + kr) * Cn + kcp * 32;
    #pragma unroll
    for (int i = 0; i < 4; i++) ka[i] = ((const uint4*)src)[i];
    const unsigned short* s0p = V + (size_t)(kvbase + vrp) * Cn + vch;
    va[0] = ((const uint4*)s0p)[0];
    va[1] = ((const uint4*)s0p)[1];
    va[2] = ((const uint4*)(s0p + Cn))[0];
    va[3] = ((const uint4*)(s0p + Cn))[1];
  }

  for (int step = 0; step < NSTEP; step++) {
    { // staged regs -> LDS (R2 layouts)
      uint4* dst = (uint4*)&Ks[kr][kcp * 32];
      #pragma unroll
      for (int i = 0; i < 4; i++) dst[i] = ka[i];
      union { uint4 v[2]; unsigned short u[16]; } r0, r1;
      r0.v[0] = va[0]; r0.v[1] = va[1];
      r1.v[0] = va[2]; r1.v[1] = va[3];
      #pragma unroll
      for (int j = 0; j < 16; j++) {
        unsigned int pack = (unsigned int)r0.u[j] | ((unsigned int)r1.u[j] << 16);
        *(unsigned int*)&Vt[vch + j][vrp] = pack;
      }
    }
    __syncthreads();                         // barrier 1: LDS ready

    if (step + 1 < NSTEP) {                  // issue t+1 loads; fly under compute
      int kv1 = kvbase + (step + 1) * KVB;
      const unsigned short* src = K + (size_t)(kv1 + kr) * Cn + kcp * 32;
      #pragma unroll
      for (int i = 0; i < 4; i++) ka[i] = ((const uint4*)src)[i];
      const unsigned short* s0p = V + (size_t)(kv1 + vrp) * Cn + vch;
      va[0] = ((const uint4*)s0p)[0];
      va[1] = ((const uint4*)s0p)[1];
      va[2] = ((const uint4*)(s0p + Cn))[0];
      va[3] = ((const uint4*)(s0p + Cn))[1];
    }

    // S = Q K^T over two 16-col tiles
    f32x4 s0 = (f32x4){0.f, 0.f, 0.f, 0.f};
    f32x4 s1 = (f32x4){0.f, 0.f, 0.f, 0.f};
    #pragma unroll
    for (int kk = 0; kk < 8; kk++) {
      short8 b0 = *(const short8*)&Ks[l15][kk * 32 + l4 * 8];
      short8 b1 = *(const short8*)&Ks[16 + l15][kk * 32 + l4 * 8];
      s0 = mfma16(qf[kk], b0, s0);
      s1 = mfma16(qf[kk], b1, s1);
    }

    // online softmax (rows = l4*4+i, cols spread over 16 lanes)
    float p0[4], p1[4], al[4];
    #pragma unroll
    for (int i = 0; i < 4; i++) {
      float a0 = s0[i] * scl, a1 = s1[i] * scl;
      float mt = fmaxf(a0, a1);
      mt = fmaxf(mt, __shfl_xor(mt, 1));
      mt = fmaxf(mt, __shfl_xor(mt, 2));
      mt = fmaxf(mt, __shfl_xor(mt, 4));
      mt = fmaxf(mt, __shfl_xor(mt, 8));
      float mn = fmaxf(m_r[i], mt);
      float a = __expf(m_r[i] - mn);
      m_r[i] = mn; al[i] = a;
      p0[i] = __expf(a0 - mn);
      p1[i] = __expf(a1 - mn);
      float r = p0[i] + p1[i];
      r += __shfl_xor(r, 1); r += __shfl_xor(r, 2);
      r += __shfl_xor(r, 4); r += __shfl_xor(r, 8);
      l_r[i] = l_r[i] * a + r;
    }
    // P -> LDS (bf16) in A-fragment layout
    #pragma unroll
    for (int i = 0; i < 4; i++) {
      int row = l4 * 4 + i;
      Pl[wave][row][l15]      = f2bf(p0[i]);
      Pl[wave][row][16 + l15] = f2bf(p1[i]);
    }
    // rescale O
    #pragma unroll
    for (int ct = 0; ct < 16; ct++)
      #pragma unroll
      for (int i = 0; i < 4; i++) acc_o[ct][i] *= al[i];

    // PV
    short8 pf = *(const short8*)&Pl[wave][l15][l4 * 8];
    #pragma unroll
    for (int ct = 0; ct < 16; ct++) {
      short8 vf = *(const short8*)&Vt[ct * 16 + l15][l4 * 8];
      acc_o[ct] = mfma16(pf, vf, acc_o[ct]);
    }
    __syncthreads();                         // barrier 2: reads done
  }

  // write unnormalized partials + (m,l)
  float* ob = Opart + ((size_t)(sp * Bn + b) * Nn) * Cn;
  #pragma unroll
  for (int ct = 0; ct < 16; ct++) {
    int c = ct * 16 + l15;
    #pragma unroll
    for (int i = 0; i < 4; i++) {
      int nn = q0 + l4 * 4 + i;
      ob[(size_t)nn * Cn + c] = acc_o[ct][i];
    }
  }
  if (l15 == 0) {
    #pragma unroll
    for (int i = 0; i < 4; i++) {
      int nn = q0 + l4 * 4 + i;
      size_t mb = (((size_t)sp * Bn + b) * Nn + nn) * 2;
      ml[mb]     = m_r[i];
      ml[mb + 1] = l_r[i];
    }
  }
}

// ---------------------------------------------------------------------------
// 6) Combine splits + out = gamma*att + xg, transposed to [b][c][n] via LDS
// ---------------------------------------------------------------------------
__global__ __launch_bounds__(256) void combine_kernel(
    const float* __restrict__ Opart, const float* __restrict__ ml,
    const float* __restrict__ xg, const float* __restrict__ gamma,
    float* __restrict__ out) {
  __shared__ float T[256][17];
  const int tid = threadIdx.x;
  const int n0 = blockIdx.x * 16;
  const int b = blockIdx.y;
  const float g = gamma[0];
  for (int r = 0; r < 16; r++) {
    int n = n0 + r;
    float msp[SPLIT], lsp[SPLIT];
    float mm = -1e30f;
    #pragma unroll
    for (int s = 0; s < SPLIT; s++) {
      size_t mb = (((size_t)s * Bn + b) * Nn + n) * 2;
      msp[s] = ml[mb]; lsp[s] = ml[mb + 1];
      mm = fmaxf(mm, msp[s]);
    }
    float denom = 0.f, w[SPLIT];
    #pragma unroll
    for (int s = 0; s < SPLIT; s++) { w[s] = __expf(msp[s] - mm); denom += w[s] * lsp[s]; }
    float inv = 1.f / denom;
    float acc = 0.f;
    #pragma unroll
    for (int s = 0; s < SPLIT; s++)
      acc += w[s] * Opart[(((size_t)s * Bn + b) * Nn + n) * Cn + tid];
    T[tid][r] = acc * inv;
  }
  __syncthreads();
  const int c = tid;
  const float4* xg4 = (const float4*)(xg + ((size_t)(b * Cn + c)) * Nn + n0);
  float4* op = (float4*)(out + ((size_t)(b * Cn + c)) * Nn + n0);
  #pragma unroll
  for (int r4 = 0; r4 < 4; r4++) {
    float4 xv = xg4[r4];
    float4 vv;
    vv.x = g * T[c][r4 * 4 + 0] + xv.x;
    vv.y = g * T[c][r4 * 4 + 1] + xv.y;
    vv.z = g * T[c][r4 * 4 + 2] + xv.z;
    vv.w = g * T[c][r4 * 4 + 3] + xv.w;
    op[r4] = vv;
  }
}

// ---------------------------------------------------------------------------
extern "C" void kernel_launch(void* const* d_in, const int* in_sizes, int n_in,
                              void* d_out, int out_size, void* d_ws, size_t ws_size,
                              hipStream_t stream) {
  const float* x   = (const float*)d_in[0];
  const float* w1  = (const float*)d_in[1];
  const float* b1  = (const float*)d_in[2];
  const float* w2i = (const float*)d_in[3];
  const float* b2  = (const float*)d_in[4];
  const float* w3  = (const float*)d_in[5];
  const float* b3  = (const float*)d_in[6];
  const float* w4  = (const float*)d_in[7];
  const float* b4  = (const float*)d_in[8];
  const float* wq  = (const float*)d_in[9];
  const float* bq  = (const float*)d_in[10];
  const float* wk  = (const float*)d_in[11];
  const float* bk  = (const float*)d_in[12];
  const float* wv  = (const float*)d_in[13];
  const float* bv  = (const float*)d_in[14];
  const float* qs  = (const float*)d_in[15];
  const float* qb  = (const float*)d_in[16];
  const float* ks  = (const float*)d_in[17];
  const float* kb  = (const float*)d_in[18];
  const float* vs  = (const float*)d_in[19];
  const float* vb  = (const float*)d_in[20];
  const float* gamma = (const float*)d_in[21];
  float* out = (float*)d_out;

  char* ws = (char*)d_ws;
  float* xg             = (float*)(ws + 0);                  //  8.39 MB
  unsigned short* xgT   = (unsigned short*)(ws + 8388608);   //  4.19 MB
  unsigned short* w2b   = (unsigned short*)(ws + 12582912);  //  1.18 MB
  unsigned short* qkv   = (unsigned short*)(ws + 13762560);  // 12.58 MB
  float* Opart          = (float*)(ws + 26345472);           // 33.55 MB (float, SPLIT=4)
  float* ml             = (float*)(ws + 59899904);           //  0.26 MB (end 60.2MB)

  prep_w_kernel<<<dim3(2304), dim3(256), 0, stream>>>(wq, wk, wv, w2b);
  gated_kernel<<<dim3(64, 4, 2), dim3(256), 0, stream>>>(
      x, w1, b1, w2i, b2, w3, b3, w4, b4, xg, xgT);
  qkvconv_ln_kernel<<<dim3(64, 2, 3), dim3(256), 0, stream>>>(
      xgT, w2b, bq, bk, bv, qs, qb, ks, kb, vs, vb, qkv);
  flash_kernel<<<dim3(64, 2, SPLIT), dim3(256), 0, stream>>>(qkv, Opart, ml);
  combine_kernel<<<dim3(256, 2), dim3(256), 0, stream>>>(Opart, ml, xg, gamma, out);
}

// Round 14
// 163.811 us; speedup vs baseline: 1.1047x; 1.1047x over previous
//
#include <hip/hip_runtime.h>

// Problem constants
#define Bn 2
#define Cn 256
#define Nn 4096
#define SPLIT 4
#define KVB 32

typedef __attribute__((ext_vector_type(8))) short short8;
typedef __attribute__((ext_vector_type(4))) float f32x4;

__device__ __forceinline__ unsigned short f2bf(float f) {
  union { float f; unsigned int u; } v; v.f = f;
  unsigned int r = (v.u + 0x7FFFu + ((v.u >> 16) & 1u)) >> 16;
  return (unsigned short)r;
}
__device__ __forceinline__ float bf2f(unsigned short u) {
  union { unsigned int i; float f; } v; v.i = ((unsigned int)u) << 16; return v.f;
}

__device__ __forceinline__ f32x4 mfma16(short8 a, short8 b, f32x4 c) {
  return __builtin_amdgcn_mfma_f32_16x16x32_bf16(a, b, c, 0, 0, 0);
}

// ---------------------------------------------------------------------------
// 1) Transpose conv weights [co][ci][t] -> bf16 w2[tensor][t][co][ci]
// ---------------------------------------------------------------------------
__global__ void prep_w_kernel(const float* __restrict__ wq,
                              const float* __restrict__ wk,
                              const float* __restrict__ wv,
                              unsigned short* __restrict__ w2) {
  int idx = blockIdx.x * 256 + threadIdx.x;           // 3*3*256*256 = 589824
  int tensor = idx / 196608;
  int rem = idx % 196608;
  int t  = rem >> 16;
  int co = (rem >> 8) & 255;
  int ci = rem & 255;
  const float* w = (tensor == 0) ? wq : (tensor == 1) ? wk : wv;
  w2[idx] = f2bf(w[(co * 256 + ci) * 3 + t]);
}

// ---------------------------------------------------------------------------
// 2) Gated channel-split 1x1x1 convs + SiLU.  fp32 (feeds output directly).
//    Writes xg fp32 [b][c][n] and xgT bf16 [b][n][c].
// ---------------------------------------------------------------------------
__global__ __launch_bounds__(256) void gated_kernel(
    const float* __restrict__ x,
    const float* __restrict__ w1, const float* __restrict__ b1,
    const float* __restrict__ w2, const float* __restrict__ b2,
    const float* __restrict__ w3, const float* __restrict__ b3,
    const float* __restrict__ w4, const float* __restrict__ b4,
    float* __restrict__ xg, unsigned short* __restrict__ xgT) {
  __shared__ float Wl[64][65];
  __shared__ float Xl[64][65];
  __shared__ unsigned short Yl[64][72];
  const int tid = threadIdx.x;
  const int n0 = blockIdx.x * 64;
  const int q  = blockIdx.y;
  const int b  = blockIdx.z;
  const float* wsel = (q == 0) ? w1 : (q == 1) ? w2 : (q == 2) ? w3 : w4;
  const float* bsel = (q == 0) ? b1 : (q == 1) ? b2 : (q == 2) ? b3 : b4;

  #pragma unroll
  for (int it = 0; it < 4; it++) {
    int i = (tid + it * 256) * 4;
    float4 v = *(const float4*)(wsel + i);
    int co = i >> 6, ci = i & 63;
    Wl[co][ci] = v.x; Wl[co][ci + 1] = v.y; Wl[co][ci + 2] = v.z; Wl[co][ci + 3] = v.w;
  }
  {
    int ci = tid >> 2, part = tid & 3;
    const float* src = x + ((size_t)(b * Cn + q * 64 + ci)) * Nn + n0 + part * 16;
    #pragma unroll
    for (int j = 0; j < 4; j++) {
      float4 v = ((const float4*)src)[j];
      float* dst = &Xl[ci][part * 16 + j * 4];
      dst[0] = v.x; dst[1] = v.y; dst[2] = v.z; dst[3] = v.w;
    }
  }
  __syncthreads();
  const int co = tid >> 2, npart = tid & 3;
  float acc[16];
  {
    float bias = bsel[co];
    #pragma unroll
    for (int j = 0; j < 16; j++) acc[j] = bias;
  }
  for (int ci = 0; ci < 64; ci++) {
    float wv_ = Wl[co][ci];
    const float* xr = &Xl[ci][npart * 16];
    #pragma unroll
    for (int j = 0; j < 16; j++) acc[j] += wv_ * xr[j];
  }
  float* xgp = xg + ((size_t)(b * Cn + q * 64 + co)) * Nn + n0 + npart * 16;
  #pragma unroll
  for (int j = 0; j < 16; j++) {
    float v = acc[j];
    float s = v / (1.f + __expf(-v));   // SiLU
    xgp[j] = s;
    Yl[npart * 16 + j][co] = f2bf(s);
  }
  __syncthreads();
  { // transpose-out: 4 threads per row, 16 channels each -> full 64x64 tile
    int r = tid >> 2, cp = tid & 3;
    union { unsigned short u[16]; uint4 v[2]; } pk;
    #pragma unroll
    for (int j = 0; j < 16; j++) pk.u[j] = Yl[r][cp * 16 + j];
    uint4* dst = (uint4*)(xgT + ((size_t)(b * Nn + n0 + r)) * Cn + q * 64 + cp * 16);
    dst[0] = pk.v[0];
    dst[1] = pk.v[1];
  }
}

// ---------------------------------------------------------------------------
// 3) QKV directional convs + fused channel LayerNorm.  K-chunk = 64
//    (12 iterations, 24 barriers), padded LDS stride 72 (9 slots -> 2-way).
// ---------------------------------------------------------------------------
__global__ __launch_bounds__(256) void qkvconv_ln_kernel(
    const unsigned short* __restrict__ xgT, const unsigned short* __restrict__ w2,
    const float* __restrict__ bq, const float* __restrict__ bk,
    const float* __restrict__ bv,
    const float* __restrict__ qs, const float* __restrict__ qb,
    const float* __restrict__ ks, const float* __restrict__ kb,
    const float* __restrict__ vs, const float* __restrict__ vb,
    unsigned short* __restrict__ qkv) {
  __shared__ unsigned short Al[64 * 72];
  __shared__ unsigned short Bl[256 * 72];
  const int tid = threadIdx.x;
  const int lane = tid & 63, wave = tid >> 6;
  const int l15 = lane & 15, l4 = lane >> 4;
  const int n0  = blockIdx.x * 64;
  const int b = blockIdx.y;
  const int tensor = blockIdx.z;
  const int cstride = (tensor == 0) ? 16 : (tensor == 1) ? 1 : 256;   // H, W, D
  const float* bias = (tensor == 0) ? bq : (tensor == 1) ? bk : bv;
  const float* lsc = (tensor == 0) ? qs : (tensor == 1) ? ks : vs;
  const float* lbi = (tensor == 0) ? qb : (tensor == 1) ? kb : vb;
  const unsigned short* wbase = w2 + (size_t)tensor * 196608;
  const unsigned short* xbase = xgT + (size_t)b * Nn * Cn;

  f32x4 acc[16];
  #pragma unroll
  for (int i = 0; i < 16; i++) acc[i] = (f32x4){0.f, 0.f, 0.f, 0.f};

  const int arow = tid >> 2, akp = tid & 3;     // A staging: row, 16-ch chunk
  const int n = n0 + arow;
  const int coordv = (n / cstride) & 15;        // coordinate along conv axis

  for (int kc = 0; kc < 12; kc++) {             // 12 chunks of K=64
    int t = kc >> 2;
    int cib = (kc & 3) * 64;
    int shift = t - 1;
    int c2 = coordv + shift;
    { // A: 64 rows x 64ch, 16 ch (2 x uint4) per thread
      const unsigned short* asrc =
          xbase + ((size_t)(n + shift * cstride)) * Cn + cib + akp * 16;
      uint4 av0 = (c2 >= 0 && c2 < 16) ? ((const uint4*)asrc)[0] : (uint4){0, 0, 0, 0};
      uint4 av1 = (c2 >= 0 && c2 < 16) ? ((const uint4*)asrc)[1] : (uint4){0, 0, 0, 0};
      uint4* ad = (uint4*)(Al + arow * 72 + akp * 16);
      ad[0] = av0; ad[1] = av1;
    }
    { // B: 256 rows x 64ch, rows tid>>2 + 64i, 16 ch per thread per row
      #pragma unroll
      for (int i = 0; i < 4; i++) {
        int row = (tid >> 2) + 64 * i;
        const unsigned short* bsrc =
            wbase + ((size_t)(t * 256 + row)) * 256 + cib + akp * 16;
        uint4* bd = (uint4*)(Bl + row * 72 + akp * 16);
        bd[0] = ((const uint4*)bsrc)[0];
        bd[1] = ((const uint4*)bsrc)[1];
      }
    }
    __syncthreads();
    int arowf = wave * 16 + l15;
    #pragma unroll
    for (int kk = 0; kk < 2; kk++) {
      short8 af = *(const short8*)(Al + arowf * 72 + kk * 32 + l4 * 8);
      #pragma unroll
      for (int ct = 0; ct < 16; ct++) {
        int brow = ct * 16 + l15;
        short8 bf = *(const short8*)(Bl + brow * 72 + kk * 32 + l4 * 8);
        acc[ct] = mfma16(af, bf, acc[ct]);
      }
    }
    __syncthreads();
  }

  // bias + channel-LN per row (rows r = l4*4+i, cols ct*16+l15)
  float bv_[16], scv[16], lbv[16];
  #pragma unroll
  for (int ct = 0; ct < 16; ct++) {
    int c = ct * 16 + l15;
    bv_[ct] = bias[c]; scv[ct] = lsc[c]; lbv[ct] = lbi[c];
  }
  unsigned short* ob = qkv + ((size_t)(tensor * Bn + b) * Nn) * Cn;
  #pragma unroll
  for (int i = 0; i < 4; i++) {
    float s = 0.f, s2 = 0.f;
    #pragma unroll
    for (int ct = 0; ct < 16; ct++) {
      float v = acc[ct][i] + bv_[ct];
      s += v; s2 += v * v;
    }
    s  += __shfl_xor(s, 1);  s  += __shfl_xor(s, 2);
    s  += __shfl_xor(s, 4);  s  += __shfl_xor(s, 8);
    s2 += __shfl_xor(s2, 1); s2 += __shfl_xor(s2, 2);
    s2 += __shfl_xor(s2, 4); s2 += __shfl_xor(s2, 8);
    float mean = s * (1.f / 256.f);
    float var  = s2 * (1.f / 256.f) - mean * mean;
    float inv  = rsqrtf(var + 1e-5f);
    int nn = n0 + wave * 16 + l4 * 4 + i;
    unsigned short* orow = ob + (size_t)nn * Cn;
    #pragma unroll
    for (int ct = 0; ct < 16; ct++) {
      float v = acc[ct][i] + bv_[ct];
      orow[ct * 16 + l15] = f2bf((v - mean) * inv * scv[ct] + lbv[ct]);
    }
  }
}

// ---------------------------------------------------------------------------
// 5) Flash attention partials — EXACT R2/R12 configuration except Opart is
//    written bf16 (write-side only; K/V read pattern untouched).
// ---------------------------------------------------------------------------
__global__ __launch_bounds__(256, 2) void flash_kernel(
    const unsigned short* __restrict__ qkv, unsigned short* __restrict__ Opart,
    float* __restrict__ ml) {
  __shared__ unsigned short Ks[KVB][264];    // row-major K tile (pad 8)
  __shared__ unsigned short Vt[256][40];     // V transposed [c][k] (pad 8)
  __shared__ unsigned short Pl[4][16][40];   // per-wave P tile
  const int tid = threadIdx.x, lane = tid & 63, wave = tid >> 6;
  const int l15 = lane & 15, l4 = lane >> 4;
  const int qt = blockIdx.x, b = blockIdx.y, sp = blockIdx.z;
  const unsigned short* Q = qkv + (size_t)(0 * Bn + b) * Nn * Cn;
  const unsigned short* K = qkv + (size_t)(1 * Bn + b) * Nn * Cn;
  const unsigned short* V = qkv + (size_t)(2 * Bn + b) * Nn * Cn;
  const int q0 = qt * 64 + wave * 16;

  short8 qf[8];
  {
    const unsigned short* qp = Q + (size_t)(q0 + l15) * Cn + l4 * 8;
    #pragma unroll
    for (int kk = 0; kk < 8; kk++) qf[kk] = *(const short8*)(qp + kk * 32);
  }
  f32x4 acc_o[16];
  #pragma unroll
  for (int i = 0; i < 16; i++) acc_o[i] = (f32x4){0.f, 0.f, 0.f, 0.f};
  float m_r[4], l_r[4];
  #pragma unroll
  for (int i = 0; i < 4; i++) { m_r[i] = -1e30f; l_r[i] = 0.f; }

  const int kvbase = sp * (Nn / SPLIT);
  const float scl = 0.0625f;                  // 1/sqrt(256)

  for (int step = 0; step < (Nn / SPLIT) / KVB; step++) {
    int kv0 = kvbase + step * KVB;
    { // stage K rows (coalesced 64B per thread)
      int r = tid >> 3, cp = tid & 7;
      const unsigned short* src = K + (size_t)(kv0 + r) * Cn + cp * 32;
      uint4* dst = (uint4*)&Ks[r][cp * 32];
      #pragma unroll
      for (int i = 0; i < 4; i++) dst[i] = ((const uint4*)src)[i];
    }
    { // stage V transposed: 2 k-rows x 16 c per thread, packed b32 writes
      int rp = (tid & 15) * 2, ch = (tid >> 4) * 16;
      const unsigned short* s0p = V + (size_t)(kv0 + rp) * Cn + ch;
      const unsigned short* s1p = s0p + Cn;
      union { uint4 v[2]; unsigned short u[16]; } r0, r1;
      r0.v[0] = ((const uint4*)s0p)[0]; r0.v[1] = ((const uint4*)s0p)[1];
      r1.v[0] = ((const uint4*)s1p)[0]; r1.v[1] = ((const uint4*)s1p)[1];
      #pragma unroll
      for (int j = 0; j < 16; j++) {
        unsigned int pack = (unsigned int)r0.u[j] | ((unsigned int)r1.u[j] << 16);
        *(unsigned int*)&Vt[ch + j][rp] = pack;
      }
    }
    __syncthreads();

    // S = Q K^T over two 16-col tiles
    f32x4 s0 = (f32x4){0.f, 0.f, 0.f, 0.f};
    f32x4 s1 = (f32x4){0.f, 0.f, 0.f, 0.f};
    #pragma unroll
    for (int kk = 0; kk < 8; kk++) {
      short8 b0 = *(const short8*)&Ks[l15][kk * 32 + l4 * 8];
      short8 b1 = *(const short8*)&Ks[16 + l15][kk * 32 + l4 * 8];
      s0 = mfma16(qf[kk], b0, s0);
      s1 = mfma16(qf[kk], b1, s1);
    }

    // online softmax (rows = l4*4+i, cols spread over 16 lanes)
    float p0[4], p1[4], al[4];
    #pragma unroll
    for (int i = 0; i < 4; i++) {
      float a0 = s0[i] * scl, a1 = s1[i] * scl;
      float mt = fmaxf(a0, a1);
      mt = fmaxf(mt, __shfl_xor(mt, 1));
      mt = fmaxf(mt, __shfl_xor(mt, 2));
      mt = fmaxf(mt, __shfl_xor(mt, 4));
      mt = fmaxf(mt, __shfl_xor(mt, 8));
      float mn = fmaxf(m_r[i], mt);
      float a = __expf(m_r[i] - mn);
      m_r[i] = mn; al[i] = a;
      p0[i] = __expf(a0 - mn);
      p1[i] = __expf(a1 - mn);
      float r = p0[i] + p1[i];
      r += __shfl_xor(r, 1); r += __shfl_xor(r, 2);
      r += __shfl_xor(r, 4); r += __shfl_xor(r, 8);
      l_r[i] = l_r[i] * a + r;
    }
    // P -> LDS (bf16) in A-fragment layout
    #pragma unroll
    for (int i = 0; i < 4; i++) {
      int row = l4 * 4 + i;
      Pl[wave][row][l15]      = f2bf(p0[i]);
      Pl[wave][row][16 + l15] = f2bf(p1[i]);
    }
    // rescale O
    #pragma unroll
    for (int ct = 0; ct < 16; ct++)
      #pragma unroll
      for (int i = 0; i < 4; i++) acc_o[ct][i] *= al[i];

    // PV
    short8 pf = *(const short8*)&Pl[wave][l15][l4 * 8];
    #pragma unroll
    for (int ct = 0; ct < 16; ct++) {
      short8 vf = *(const short8*)&Vt[ct * 16 + l15][l4 * 8];
      acc_o[ct] = mfma16(pf, vf, acc_o[ct]);
    }
    __syncthreads();
  }

  // write unnormalized partials (bf16) + (m,l)
  unsigned short* ob = Opart + ((size_t)(sp * Bn + b) * Nn) * Cn;
  #pragma unroll
  for (int ct = 0; ct < 16; ct++) {
    int c = ct * 16 + l15;
    #pragma unroll
    for (int i = 0; i < 4; i++) {
      int nn = q0 + l4 * 4 + i;
      ob[(size_t)nn * Cn + c] = f2bf(acc_o[ct][i]);
    }
  }
  if (l15 == 0) {
    #pragma unroll
    for (int i = 0; i < 4; i++) {
      int nn = q0 + l4 * 4 + i;
      size_t mb = (((size_t)sp * Bn + b) * Nn + nn) * 2;
      ml[mb]     = m_r[i];
      ml[mb + 1] = l_r[i];
    }
  }
}

// ---------------------------------------------------------------------------
// 6) Combine splits + out = gamma*att + xg, transposed to [b][c][n] via LDS
// ---------------------------------------------------------------------------
__global__ __launch_bounds__(256) void combine_kernel(
    const unsigned short* __restrict__ Opart, const float* __restrict__ ml,
    const float* __restrict__ xg, const float* __restrict__ gamma,
    float* __restrict__ out) {
  __shared__ float T[256][17];
  const int tid = threadIdx.x;
  const int n0 = blockIdx.x * 16;
  const int b = blockIdx.y;
  const float g = gamma[0];
  for (int r = 0; r < 16; r++) {
    int n = n0 + r;
    float msp[SPLIT], lsp[SPLIT];
    float mm = -1e30f;
    #pragma unroll
    for (int s = 0; s < SPLIT; s++) {
      size_t mb = (((size_t)s * Bn + b) * Nn + n) * 2;
      msp[s] = ml[mb]; lsp[s] = ml[mb + 1];
      mm = fmaxf(mm, msp[s]);
    }
    float denom = 0.f, w[SPLIT];
    #pragma unroll
    for (int s = 0; s < SPLIT; s++) { w[s] = __expf(msp[s] - mm); denom += w[s] * lsp[s]; }
    float inv = 1.f / denom;
    float acc = 0.f;
    #pragma unroll
    for (int s = 0; s < SPLIT; s++)
      acc += w[s] * bf2f(Opart[(((size_t)s * Bn + b) * Nn + n) * Cn + tid]);
    T[tid][r] = acc * inv;
  }
  __syncthreads();
  const int c = tid;
  const float4* xg4 = (const float4*)(xg + ((size_t)(b * Cn + c)) * Nn + n0);
  float4* op = (float4*)(out + ((size_t)(b * Cn + c)) * Nn + n0);
  #pragma unroll
  for (int r4 = 0; r4 < 4; r4++) {
    float4 xv = xg4[r4];
    float4 vv;
    vv.x = g * T[c][r4 * 4 + 0] + xv.x;
    vv.y = g * T[c][r4 * 4 + 1] + xv.y;
    vv.z = g * T[c][r4 * 4 + 2] + xv.z;
    vv.w = g * T[c][r4 * 4 + 3] + xv.w;
    op[r4] = vv;
  }
}

// ---------------------------------------------------------------------------
extern "C" void kernel_launch(void* const* d_in, const int* in_sizes, int n_in,
                              void* d_out, int out_size, void* d_ws, size_t ws_size,
                              hipStream_t stream) {
  const float* x   = (const float*)d_in[0];
  const float* w1  = (const float*)d_in[1];
  const float* b1  = (const float*)d_in[2];
  const float* w2i = (const float*)d_in[3];
  const float* b2  = (const float*)d_in[4];
  const float* w3  = (const float*)d_in[5];
  const float* b3  = (const float*)d_in[6];
  const float* w4  = (const float*)d_in[7];
  const float* b4  = (const float*)d_in[8];
  const float* wq  = (const float*)d_in[9];
  const float* bq  = (const float*)d_in[10];
  const float* wk  = (const float*)d_in[11];
  const float* bk  = (const float*)d_in[12];
  const float* wv  = (const float*)d_in[13];
  const float* bv  = (const float*)d_in[14];
  const float* qs  = (const float*)d_in[15];
  const float* qb  = (const float*)d_in[16];
  const float* ks  = (const float*)d_in[17];
  const float* kb  = (const float*)d_in[18];
  const float* vs  = (const float*)d_in[19];
  const float* vb  = (const float*)d_in[20];
  const float* gamma = (const float*)d_in[21];
  float* out = (float*)d_out;

  char* ws = (char*)d_ws;
  float* xg             = (float*)(ws + 0);                  //  8.39 MB
  unsigned short* xgT   = (unsigned short*)(ws + 8388608);   //  4.19 MB
  unsigned short* w2b   = (unsigned short*)(ws + 12582912);  //  1.18 MB
  unsigned short* qkv   = (unsigned short*)(ws + 13762560);  // 12.58 MB
  unsigned short* Opart = (unsigned short*)(ws + 26345472);  // 16.78 MB (bf16, SPLIT=4)
  float* ml             = (float*)(ws + 43122688);           //  0.26 MB (end 43.4MB)

  prep_w_kernel<<<dim3(2304), dim3(256), 0, stream>>>(wq, wk, wv, w2b);
  gated_kernel<<<dim3(64, 4, 2), dim3(256), 0, stream>>>(
      x, w1, b1, w2i, b2, w3, b3, w4, b4, xg, xgT);
  qkvconv_ln_kernel<<<dim3(64, 2, 3), dim3(256), 0, stream>>>(
      xgT, w2b, bq, bk, bv, qs, qb, ks, kb, vs, vb, qkv);
  flash_kernel<<<dim3(64, 2, SPLIT), dim3(256), 0, stream>>>(qkv, Opart, ml);
  combine_kernel<<<dim3(256, 2), dim3(256), 0, stream>>>(Opart, ml, xg, gamma, out);
}

// Round 16
// 159.213 us; speedup vs baseline: 1.1366x; 1.0289x over previous
//
#include <hip/hip_runtime.h>

// Problem constants
#define Bn 2
#define Cn 256
#define Nn 4096
#define SPLIT 4
#define KVB 64
#define NSTEP ((Nn / SPLIT) / KVB)

typedef __attribute__((ext_vector_type(8))) short short8;
typedef __attribute__((ext_vector_type(4))) float f32x4;

__device__ __forceinline__ unsigned short f2bf(float f) {
  union { float f; unsigned int u; } v; v.f = f;
  unsigned int r = (v.u + 0x7FFFu + ((v.u >> 16) & 1u)) >> 16;
  return (unsigned short)r;
}
__device__ __forceinline__ float bf2f(unsigned short u) {
  union { unsigned int i; float f; } v; v.i = ((unsigned int)u) << 16; return v.f;
}

__device__ __forceinline__ f32x4 mfma16(short8 a, short8 b, f32x4 c) {
  return __builtin_amdgcn_mfma_f32_16x16x32_bf16(a, b, c, 0, 0, 0);
}

// ---------------------------------------------------------------------------
// 1) Transpose conv weights [co][ci][t] -> bf16 w2[tensor][t][co][ci]
// ---------------------------------------------------------------------------
__global__ void prep_w_kernel(const float* __restrict__ wq,
                              const float* __restrict__ wk,
                              const float* __restrict__ wv,
                              unsigned short* __restrict__ w2) {
  int idx = blockIdx.x * 256 + threadIdx.x;           // 3*3*256*256 = 589824
  int tensor = idx / 196608;
  int rem = idx % 196608;
  int t  = rem >> 16;
  int co = (rem >> 8) & 255;
  int ci = rem & 255;
  const float* w = (tensor == 0) ? wq : (tensor == 1) ? wk : wv;
  w2[idx] = f2bf(w[(co * 256 + ci) * 3 + t]);
}

// ---------------------------------------------------------------------------
// 2) Gated channel-split 1x1x1 convs + SiLU.  fp32 (feeds output directly).
//    Writes xg fp32 [b][c][n] and xgT bf16 [b][n][c].
// ---------------------------------------------------------------------------
__global__ __launch_bounds__(256) void gated_kernel(
    const float* __restrict__ x,
    const float* __restrict__ w1, const float* __restrict__ b1,
    const float* __restrict__ w2, const float* __restrict__ b2,
    const float* __restrict__ w3, const float* __restrict__ b3,
    const float* __restrict__ w4, const float* __restrict__ b4,
    float* __restrict__ xg, unsigned short* __restrict__ xgT) {
  __shared__ float Wl[64][65];
  __shared__ float Xl[64][65];
  __shared__ unsigned short Yl[64][72];
  const int tid = threadIdx.x;
  const int n0 = blockIdx.x * 64;
  const int q  = blockIdx.y;
  const int b  = blockIdx.z;
  const float* wsel = (q == 0) ? w1 : (q == 1) ? w2 : (q == 2) ? w3 : w4;
  const float* bsel = (q == 0) ? b1 : (q == 1) ? b2 : (q == 2) ? b3 : b4;

  #pragma unroll
  for (int it = 0; it < 4; it++) {
    int i = (tid + it * 256) * 4;
    float4 v = *(const float4*)(wsel + i);
    int co = i >> 6, ci = i & 63;
    Wl[co][ci] = v.x; Wl[co][ci + 1] = v.y; Wl[co][ci + 2] = v.z; Wl[co][ci + 3] = v.w;
  }
  {
    int ci = tid >> 2, part = tid & 3;
    const float* src = x + ((size_t)(b * Cn + q * 64 + ci)) * Nn + n0 + part * 16;
    #pragma unroll
    for (int j = 0; j < 4; j++) {
      float4 v = ((const float4*)src)[j];
      float* dst = &Xl[ci][part * 16 + j * 4];
      dst[0] = v.x; dst[1] = v.y; dst[2] = v.z; dst[3] = v.w;
    }
  }
  __syncthreads();
  const int co = tid >> 2, npart = tid & 3;
  float acc[16];
  {
    float bias = bsel[co];
    #pragma unroll
    for (int j = 0; j < 16; j++) acc[j] = bias;
  }
  for (int ci = 0; ci < 64; ci++) {
    float wv_ = Wl[co][ci];
    const float* xr = &Xl[ci][npart * 16];
    #pragma unroll
    for (int j = 0; j < 16; j++) acc[j] += wv_ * xr[j];
  }
  float* xgp = xg + ((size_t)(b * Cn + q * 64 + co)) * Nn + n0 + npart * 16;
  #pragma unroll
  for (int j = 0; j < 16; j++) {
    float v = acc[j];
    float s = v / (1.f + __expf(-v));   // SiLU
    xgp[j] = s;
    Yl[npart * 16 + j][co] = f2bf(s);
  }
  __syncthreads();
  { // transpose-out: 4 threads per row, 16 channels each -> full 64x64 tile
    int r = tid >> 2, cp = tid & 3;
    union { unsigned short u[16]; uint4 v[2]; } pk;
    #pragma unroll
    for (int j = 0; j < 16; j++) pk.u[j] = Yl[r][cp * 16 + j];
    uint4* dst = (uint4*)(xgT + ((size_t)(b * Nn + n0 + r)) * Cn + q * 64 + cp * 16);
    dst[0] = pk.v[0];
    dst[1] = pk.v[1];
  }
}

// ---------------------------------------------------------------------------
// 3) QKV directional convs + fused channel LayerNorm.  K-chunk = 64
//    (12 iterations, 24 barriers), padded LDS stride 72 (9 slots -> 2-way).
// ---------------------------------------------------------------------------
__global__ __launch_bounds__(256) void qkvconv_ln_kernel(
    const unsigned short* __restrict__ xgT, const unsigned short* __restrict__ w2,
    const float* __restrict__ bq, const float* __restrict__ bk,
    const float* __restrict__ bv,
    const float* __restrict__ qs, const float* __restrict__ qb,
    const float* __restrict__ ks, const float* __restrict__ kb,
    const float* __restrict__ vs, const float* __restrict__ vb,
    unsigned short* __restrict__ qkv) {
  __shared__ unsigned short Al[64 * 72];
  __shared__ unsigned short Bl[256 * 72];
  const int tid = threadIdx.x;
  const int lane = tid & 63, wave = tid >> 6;
  const int l15 = lane & 15, l4 = lane >> 4;
  const int n0  = blockIdx.x * 64;
  const int b = blockIdx.y;
  const int tensor = blockIdx.z;
  const int cstride = (tensor == 0) ? 16 : (tensor == 1) ? 1 : 256;   // H, W, D
  const float* bias = (tensor == 0) ? bq : (tensor == 1) ? bk : bv;
  const float* lsc = (tensor == 0) ? qs : (tensor == 1) ? ks : vs;
  const float* lbi = (tensor == 0) ? qb : (tensor == 1) ? kb : vb;
  const unsigned short* wbase = w2 + (size_t)tensor * 196608;
  const unsigned short* xbase = xgT + (size_t)b * Nn * Cn;

  f32x4 acc[16];
  #pragma unroll
  for (int i = 0; i < 16; i++) acc[i] = (f32x4){0.f, 0.f, 0.f, 0.f};

  const int arow = tid >> 2, akp = tid & 3;     // A staging: row, 16-ch chunk
  const int n = n0 + arow;
  const int coordv = (n / cstride) & 15;        // coordinate along conv axis

  for (int kc = 0; kc < 12; kc++) {             // 12 chunks of K=64
    int t = kc >> 2;
    int cib = (kc & 3) * 64;
    int shift = t - 1;
    int c2 = coordv + shift;
    { // A: 64 rows x 64ch, 16 ch (2 x uint4) per thread
      const unsigned short* asrc =
          xbase + ((size_t)(n + shift * cstride)) * Cn + cib + akp * 16;
      uint4 av0 = (c2 >= 0 && c2 < 16) ? ((const uint4*)asrc)[0] : (uint4){0, 0, 0, 0};
      uint4 av1 = (c2 >= 0 && c2 < 16) ? ((const uint4*)asrc)[1] : (uint4){0, 0, 0, 0};
      uint4* ad = (uint4*)(Al + arow * 72 + akp * 16);
      ad[0] = av0; ad[1] = av1;
    }
    { // B: 256 rows x 64ch, rows tid>>2 + 64i, 16 ch per thread per row
      #pragma unroll
      for (int i = 0; i < 4; i++) {
        int row = (tid >> 2) + 64 * i;
        const unsigned short* bsrc =
            wbase + ((size_t)(t * 256 + row)) * 256 + cib + akp * 16;
        uint4* bd = (uint4*)(Bl + row * 72 + akp * 16);
        bd[0] = ((const uint4*)bsrc)[0];
        bd[1] = ((const uint4*)bsrc)[1];
      }
    }
    __syncthreads();
    int arowf = wave * 16 + l15;
    #pragma unroll
    for (int kk = 0; kk < 2; kk++) {
      short8 af = *(const short8*)(Al + arowf * 72 + kk * 32 + l4 * 8);
      #pragma unroll
      for (int ct = 0; ct < 16; ct++) {
        int brow = ct * 16 + l15;
        short8 bf = *(const short8*)(Bl + brow * 72 + kk * 32 + l4 * 8);
        acc[ct] = mfma16(af, bf, acc[ct]);
      }
    }
    __syncthreads();
  }

  // bias + channel-LN per row (rows r = l4*4+i, cols ct*16+l15)
  float bv_[16], scv[16], lbv[16];
  #pragma unroll
  for (int ct = 0; ct < 16; ct++) {
    int c = ct * 16 + l15;
    bv_[ct] = bias[c]; scv[ct] = lsc[c]; lbv[ct] = lbi[c];
  }
  unsigned short* ob = qkv + ((size_t)(tensor * Bn + b) * Nn) * Cn;
  #pragma unroll
  for (int i = 0; i < 4; i++) {
    float s = 0.f, s2 = 0.f;
    #pragma unroll
    for (int ct = 0; ct < 16; ct++) {
      float v = acc[ct][i] + bv_[ct];
      s += v; s2 += v * v;
    }
    s  += __shfl_xor(s, 1);  s  += __shfl_xor(s, 2);
    s  += __shfl_xor(s, 4);  s  += __shfl_xor(s, 8);
    s2 += __shfl_xor(s2, 1); s2 += __shfl_xor(s2, 2);
    s2 += __shfl_xor(s2, 4); s2 += __shfl_xor(s2, 8);
    float mean = s * (1.f / 256.f);
    float var  = s2 * (1.f / 256.f) - mean * mean;
    float inv  = rsqrtf(var + 1e-5f);
    int nn = n0 + wave * 16 + l4 * 4 + i;
    unsigned short* orow = ob + (size_t)nn * Cn;
    #pragma unroll
    for (int ct = 0; ct < 16; ct++) {
      float v = acc[ct][i] + bv_[ct];
      orow[ct * 16 + l15] = f2bf((v - mean) * inv * scv[ct] + lbv[ct]);
    }
  }
}

// ---------------------------------------------------------------------------
// 5) Flash attention partials — R2/R14 skeleton (grid dim3(64,2,4), 256 thr,
//    4 waves, Q-tile 64, 2 barriers/step, direct staging, bf16 Opart) with
//    KVB = 64.  FIX vs R15: K staging copies 8 x uint4 = 128B per thread
//    (full 64-ch chunk); R15 copied only 4 -> half the K tile was garbage.
// ---------------------------------------------------------------------------
__global__ __launch_bounds__(256, 2) void flash_kernel(
    const unsigned short* __restrict__ qkv, unsigned short* __restrict__ Opart,
    float* __restrict__ ml) {
  __shared__ unsigned short Ks[KVB][264];
  __shared__ unsigned short Vt[256][72];
  __shared__ unsigned short Pl[4][16][72];
  const int tid = threadIdx.x, lane = tid & 63, wave = tid >> 6;
  const int l15 = lane & 15, l4 = lane >> 4;
  const int qt = blockIdx.x, b = blockIdx.y, sp = blockIdx.z;
  const unsigned short* Q = qkv + (size_t)(0 * Bn + b) * Nn * Cn;
  const unsigned short* K = qkv + (size_t)(1 * Bn + b) * Nn * Cn;
  const unsigned short* V = qkv + (size_t)(2 * Bn + b) * Nn * Cn;
  const int q0 = qt * 64 + wave * 16;

  short8 qf[8];
  {
    const unsigned short* qp = Q + (size_t)(q0 + l15) * Cn + l4 * 8;
    #pragma unroll
    for (int kk = 0; kk < 8; kk++) qf[kk] = *(const short8*)(qp + kk * 32);
  }
  f32x4 acc_o[16];
  #pragma unroll
  for (int i = 0; i < 16; i++) acc_o[i] = (f32x4){0.f, 0.f, 0.f, 0.f};
  float m_r[4], l_r[4];
  #pragma unroll
  for (int i = 0; i < 4; i++) { m_r[i] = -1e30f; l_r[i] = 0.f; }

  const int kvbase = sp * (Nn / SPLIT);
  const float scl = 0.0625f;                  // 1/sqrt(256)

  for (int step = 0; step < NSTEP; step++) {
    int kv0 = kvbase + step * KVB;
    { // stage K: 64 rows, 4 threads/row, contiguous 128B (8 x uint4) each
      int r = tid >> 2, cp = tid & 3;
      const unsigned short* src = K + (size_t)(kv0 + r) * Cn + cp * 64;
      uint4* dst = (uint4*)&Ks[r][cp * 64];
      #pragma unroll
      for (int i = 0; i < 8; i++) dst[i] = ((const uint4*)src)[i];
    }
    { // stage V transposed: 2 k-rows x 32 ch per thread, packed b32 writes
      int rp = (tid & 31) * 2, ch = (tid >> 5) * 32;
      const unsigned short* s0p = V + (size_t)(kv0 + rp) * Cn + ch;
      const unsigned short* s1p = s0p + Cn;
      union { uint4 v[4]; unsigned short u[32]; } r0, r1;
      #pragma unroll
      for (int i = 0; i < 4; i++) {
        r0.v[i] = ((const uint4*)s0p)[i];
        r1.v[i] = ((const uint4*)s1p)[i];
      }
      #pragma unroll
      for (int j = 0; j < 32; j++) {
        unsigned int pack = (unsigned int)r0.u[j] | ((unsigned int)r1.u[j] << 16);
        *(unsigned int*)&Vt[ch + j][rp] = pack;
      }
    }
    __syncthreads();

    // S = Q K^T over four 16-col tiles
    f32x4 s[4];
    #pragma unroll
    for (int t = 0; t < 4; t++) s[t] = (f32x4){0.f, 0.f, 0.f, 0.f};
    #pragma unroll
    for (int kk = 0; kk < 8; kk++) {
      #pragma unroll
      for (int t = 0; t < 4; t++) {
        short8 bt = *(const short8*)&Ks[t * 16 + l15][kk * 32 + l4 * 8];
        s[t] = mfma16(qf[kk], bt, s[t]);
      }
    }

    // online softmax (rows = l4*4+i, 64 cols = 4 subtiles x 16 lanes)
    float p[4][4], al[4];
    #pragma unroll
    for (int i = 0; i < 4; i++) {
      float a0 = s[0][i] * scl, a1 = s[1][i] * scl;
      float a2 = s[2][i] * scl, a3 = s[3][i] * scl;
      float mt = fmaxf(fmaxf(a0, a1), fmaxf(a2, a3));
      mt = fmaxf(mt, __shfl_xor(mt, 1));
      mt = fmaxf(mt, __shfl_xor(mt, 2));
      mt = fmaxf(mt, __shfl_xor(mt, 4));
      mt = fmaxf(mt, __shfl_xor(mt, 8));
      float mn = fmaxf(m_r[i], mt);
      float a = __expf(m_r[i] - mn);
      m_r[i] = mn; al[i] = a;
      p[0][i] = __expf(a0 - mn);
      p[1][i] = __expf(a1 - mn);
      p[2][i] = __expf(a2 - mn);
      p[3][i] = __expf(a3 - mn);
      float r = (p[0][i] + p[1][i]) + (p[2][i] + p[3][i]);
      r += __shfl_xor(r, 1); r += __shfl_xor(r, 2);
      r += __shfl_xor(r, 4); r += __shfl_xor(r, 8);
      l_r[i] = l_r[i] * a + r;
    }
    // P -> LDS (bf16) in A-fragment layout
    #pragma unroll
    for (int i = 0; i < 4; i++) {
      int row = l4 * 4 + i;
      #pragma unroll
      for (int t = 0; t < 4; t++)
        Pl[wave][row][t * 16 + l15] = f2bf(p[t][i]);
    }
    // rescale O
    #pragma unroll
    for (int ct = 0; ct < 16; ct++)
      #pragma unroll
      for (int i = 0; i < 4; i++) acc_o[ct][i] *= al[i];

    // PV over two K=32 slices
    short8 pf0 = *(const short8*)&Pl[wave][l15][l4 * 8];
    short8 pf1 = *(const short8*)&Pl[wave][l15][32 + l4 * 8];
    #pragma unroll
    for (int ct = 0; ct < 16; ct++) {
      short8 vf0 = *(const short8*)&Vt[ct * 16 + l15][l4 * 8];
      short8 vf1 = *(const short8*)&Vt[ct * 16 + l15][32 + l4 * 8];
      acc_o[ct] = mfma16(pf0, vf0, acc_o[ct]);
      acc_o[ct] = mfma16(pf1, vf1, acc_o[ct]);
    }
    __syncthreads();
  }

  // write unnormalized partials (bf16) + (m,l)
  unsigned short* ob = Opart + ((size_t)(sp * Bn + b) * Nn) * Cn;
  #pragma unroll
  for (int ct = 0; ct < 16; ct++) {
    int c = ct * 16 + l15;
    #pragma unroll
    for (int i = 0; i < 4; i++) {
      int nn = q0 + l4 * 4 + i;
      ob[(size_t)nn * Cn + c] = f2bf(acc_o[ct][i]);
    }
  }
  if (l15 == 0) {
    #pragma unroll
    for (int i = 0; i < 4; i++) {
      int nn = q0 + l4 * 4 + i;
      size_t mb = (((size_t)sp * Bn + b) * Nn + nn) * 2;
      ml[mb]     = m_r[i];
      ml[mb + 1] = l_r[i];
    }
  }
}

// ---------------------------------------------------------------------------
// 6) Combine splits + out = gamma*att + xg, transposed to [b][c][n] via LDS
// ---------------------------------------------------------------------------
__global__ __launch_bounds__(256) void combine_kernel(
    const unsigned short* __restrict__ Opart, const float* __restrict__ ml,
    const float* __restrict__ xg, const float* __restrict__ gamma,
    float* __restrict__ out) {
  __shared__ float T[256][17];
  const int tid = threadIdx.x;
  const int n0 = blockIdx.x * 16;
  const int b = blockIdx.y;
  const float g = gamma[0];
  for (int r = 0; r < 16; r++) {
    int n = n0 + r;
    float msp[SPLIT], lsp[SPLIT];
    float mm = -1e30f;
    #pragma unroll
    for (int s = 0; s < SPLIT; s++) {
      size_t mb = (((size_t)s * Bn + b) * Nn + n) * 2;
      msp[s] = ml[mb]; lsp[s] = ml[mb + 1];
      mm = fmaxf(mm, msp[s]);
    }
    float denom = 0.f, w[SPLIT];
    #pragma unroll
    for (int s = 0; s < SPLIT; s++) { w[s] = __expf(msp[s] - mm); denom += w[s] * lsp[s]; }
    float inv = 1.f / denom;
    float acc = 0.f;
    #pragma unroll
    for (int s = 0; s < SPLIT; s++)
      acc += w[s] * bf2f(Opart[(((size_t)s * Bn + b) * Nn + n) * Cn + tid]);
    T[tid][r] = acc * inv;
  }
  __syncthreads();
  const int c = tid;
  const float4* xg4 = (const float4*)(xg + ((size_t)(b * Cn + c)) * Nn + n0);
  float4* op = (float4*)(out + ((size_t)(b * Cn + c)) * Nn + n0);
  #pragma unroll
  for (int r4 = 0; r4 < 4; r4++) {
    float4 xv = xg4[r4];
    float4 vv;
    vv.x = g * T[c][r4 * 4 + 0] + xv.x;
    vv.y = g * T[c][r4 * 4 + 1] + xv.y;
    vv.z = g * T[c][r4 * 4 + 2] + xv.z;
    vv.w = g * T[c][r4 * 4 + 3] + xv.w;
    op[r4] = vv;
  }
}

// ---------------------------------------------------------------------------
extern "C" void kernel_launch(void* const* d_in, const int* in_sizes, int n_in,
                              void* d_out, int out_size, void* d_ws, size_t ws_size,
                              hipStream_t stream) {
  const float* x   = (const float*)d_in[0];
  const float* w1  = (const float*)d_in[1];
  const float* b1  = (const float*)d_in[2];
  const float* w2i = (const float*)d_in[3];
  const float* b2  = (const float*)d_in[4];
  const float* w3  = (const float*)d_in[5];
  const float* b3  = (const float*)d_in[6];
  const float* w4  = (const float*)d_in[7];
  const float* b4  = (const float*)d_in[8];
  const float* wq  = (const float*)d_in[9];
  const float* bq  = (const float*)d_in[10];
  const float* wk  = (const float*)d_in[11];
  const float* bk  = (const float*)d_in[12];
  const float* wv  = (const float*)d_in[13];
  const float* bv  = (const float*)d_in[14];
  const float* qs  = (const float*)d_in[15];
  const float* qb  = (const float*)d_in[16];
  const float* ks  = (const float*)d_in[17];
  const float* kb  = (const float*)d_in[18];
  const float* vs  = (const float*)d_in[19];
  const float* vb  = (const float*)d_in[20];
  const float* gamma = (const float*)d_in[21];
  float* out = (float*)d_out;

  char* ws = (char*)d_ws;
  float* xg             = (float*)(ws + 0);                  //  8.39 MB
  unsigned short* xgT   = (unsigned short*)(ws + 8388608);   //  4.19 MB
  unsigned short* w2b   = (unsigned short*)(ws + 12582912);  //  1.18 MB
  unsigned short* qkv   = (unsigned short*)(ws + 13762560);  // 12.58 MB
  unsigned short* Opart = (unsigned short*)(ws + 26345472);  // 16.78 MB (bf16, SPLIT=4)
  float* ml             = (float*)(ws + 43122688);           //  0.26 MB (end 43.4MB)

  prep_w_kernel<<<dim3(2304), dim3(256), 0, stream>>>(wq, wk, wv, w2b);
  gated_kernel<<<dim3(64, 4, 2), dim3(256), 0, stream>>>(
      x, w1, b1, w2i, b2, w3, b3, w4, b4, xg, xgT);
  qkvconv_ln_kernel<<<dim3(64, 2, 3), dim3(256), 0, stream>>>(
      xgT, w2b, bq, bk, bv, qs, qb, ks, kb, vs, vb, qkv);
  flash_kernel<<<dim3(64, 2, SPLIT), dim3(256), 0, stream>>>(qkv, Opart, ml);
  combine_kernel<<<dim3(256, 2), dim3(256), 0, stream>>>(Opart, ml, xg, gamma, out);
}

// Round 17
// 158.592 us; speedup vs baseline: 1.1410x; 1.0039x over previous
//
#include <hip/hip_runtime.h>

// Problem constants
#define Bn 2
#define Cn 256
#define Nn 4096
#define SPLIT 4
#define KVB 64
#define NSTEP ((Nn / SPLIT) / KVB)

typedef __attribute__((ext_vector_type(8))) short short8;
typedef __attribute__((ext_vector_type(4))) float f32x4;

__device__ __forceinline__ unsigned short f2bf(float f) {
  union { float f; unsigned int u; } v; v.f = f;
  unsigned int r = (v.u + 0x7FFFu + ((v.u >> 16) & 1u)) >> 16;
  return (unsigned short)r;
}
__device__ __forceinline__ float bf2f(unsigned short u) {
  union { unsigned int i; float f; } v; v.i = ((unsigned int)u) << 16; return v.f;
}

__device__ __forceinline__ f32x4 mfma16(short8 a, short8 b, f32x4 c) {
  return __builtin_amdgcn_mfma_f32_16x16x32_bf16(a, b, c, 0, 0, 0);
}

// ---------------------------------------------------------------------------
// 1) Transpose conv weights [co][ci][t] -> bf16 w2[tensor][t][co][ci]
// ---------------------------------------------------------------------------
__global__ void prep_w_kernel(const float* __restrict__ wq,
                              const float* __restrict__ wk,
                              const float* __restrict__ wv,
                              unsigned short* __restrict__ w2) {
  int idx = blockIdx.x * 256 + threadIdx.x;           // 3*3*256*256 = 589824
  int tensor = idx / 196608;
  int rem = idx % 196608;
  int t  = rem >> 16;
  int co = (rem >> 8) & 255;
  int ci = rem & 255;
  const float* w = (tensor == 0) ? wq : (tensor == 1) ? wk : wv;
  w2[idx] = f2bf(w[(co * 256 + ci) * 3 + t]);
}

// ---------------------------------------------------------------------------
// 2) Gated channel-split 1x1x1 convs + SiLU.  Writes ONLY xgT bf16 [b][n][c]
//    (fp32 xg eliminated; residual is added from xgT in combine).
// ---------------------------------------------------------------------------
__global__ __launch_bounds__(256) void gated_kernel(
    const float* __restrict__ x,
    const float* __restrict__ w1, const float* __restrict__ b1,
    const float* __restrict__ w2, const float* __restrict__ b2,
    const float* __restrict__ w3, const float* __restrict__ b3,
    const float* __restrict__ w4, const float* __restrict__ b4,
    unsigned short* __restrict__ xgT) {
  __shared__ float Wl[64][65];
  __shared__ float Xl[64][65];
  __shared__ unsigned short Yl[64][72];
  const int tid = threadIdx.x;
  const int n0 = blockIdx.x * 64;
  const int q  = blockIdx.y;
  const int b  = blockIdx.z;
  const float* wsel = (q == 0) ? w1 : (q == 1) ? w2 : (q == 2) ? w3 : w4;
  const float* bsel = (q == 0) ? b1 : (q == 1) ? b2 : (q == 2) ? b3 : b4;

  #pragma unroll
  for (int it = 0; it < 4; it++) {
    int i = (tid + it * 256) * 4;
    float4 v = *(const float4*)(wsel + i);
    int co = i >> 6, ci = i & 63;
    Wl[co][ci] = v.x; Wl[co][ci + 1] = v.y; Wl[co][ci + 2] = v.z; Wl[co][ci + 3] = v.w;
  }
  {
    int ci = tid >> 2, part = tid & 3;
    const float* src = x + ((size_t)(b * Cn + q * 64 + ci)) * Nn + n0 + part * 16;
    #pragma unroll
    for (int j = 0; j < 4; j++) {
      float4 v = ((const float4*)src)[j];
      float* dst = &Xl[ci][part * 16 + j * 4];
      dst[0] = v.x; dst[1] = v.y; dst[2] = v.z; dst[3] = v.w;
    }
  }
  __syncthreads();
  const int co = tid >> 2, npart = tid & 3;
  float acc[16];
  {
    float bias = bsel[co];
    #pragma unroll
    for (int j = 0; j < 16; j++) acc[j] = bias;
  }
  for (int ci = 0; ci < 64; ci++) {
    float wv_ = Wl[co][ci];
    const float* xr = &Xl[ci][npart * 16];
    #pragma unroll
    for (int j = 0; j < 16; j++) acc[j] += wv_ * xr[j];
  }
  #pragma unroll
  for (int j = 0; j < 16; j++) {
    float v = acc[j];
    float s = v / (1.f + __expf(-v));   // SiLU
    Yl[npart * 16 + j][co] = f2bf(s);
  }
  __syncthreads();
  { // transpose-out: 4 threads per row, 16 channels each -> full 64x64 tile
    int r = tid >> 2, cp = tid & 3;
    union { unsigned short u[16]; uint4 v[2]; } pk;
    #pragma unroll
    for (int j = 0; j < 16; j++) pk.u[j] = Yl[r][cp * 16 + j];
    uint4* dst = (uint4*)(xgT + ((size_t)(b * Nn + n0 + r)) * Cn + q * 64 + cp * 16);
    dst[0] = pk.v[0];
    dst[1] = pk.v[1];
  }
}

// ---------------------------------------------------------------------------
// 3) QKV directional convs + fused channel LayerNorm.  K-chunk = 64
//    (12 iterations, 24 barriers), padded LDS stride 72 (9 slots -> 2-way).
// ---------------------------------------------------------------------------
__global__ __launch_bounds__(256) void qkvconv_ln_kernel(
    const unsigned short* __restrict__ xgT, const unsigned short* __restrict__ w2,
    const float* __restrict__ bq, const float* __restrict__ bk,
    const float* __restrict__ bv,
    const float* __restrict__ qs, const float* __restrict__ qb,
    const float* __restrict__ ks, const float* __restrict__ kb,
    const float* __restrict__ vs, const float* __restrict__ vb,
    unsigned short* __restrict__ qkv) {
  __shared__ unsigned short Al[64 * 72];
  __shared__ unsigned short Bl[256 * 72];
  const int tid = threadIdx.x;
  const int lane = tid & 63, wave = tid >> 6;
  const int l15 = lane & 15, l4 = lane >> 4;
  const int n0  = blockIdx.x * 64;
  const int b = blockIdx.y;
  const int tensor = blockIdx.z;
  const int cstride = (tensor == 0) ? 16 : (tensor == 1) ? 1 : 256;   // H, W, D
  const float* bias = (tensor == 0) ? bq : (tensor == 1) ? bk : bv;
  const float* lsc = (tensor == 0) ? qs : (tensor == 1) ? ks : vs;
  const float* lbi = (tensor == 0) ? qb : (tensor == 1) ? kb : vb;
  const unsigned short* wbase = w2 + (size_t)tensor * 196608;
  const unsigned short* xbase = xgT + (size_t)b * Nn * Cn;

  f32x4 acc[16];
  #pragma unroll
  for (int i = 0; i < 16; i++) acc[i] = (f32x4){0.f, 0.f, 0.f, 0.f};

  const int arow = tid >> 2, akp = tid & 3;     // A staging: row, 16-ch chunk
  const int n = n0 + arow;
  const int coordv = (n / cstride) & 15;        // coordinate along conv axis

  for (int kc = 0; kc < 12; kc++) {             // 12 chunks of K=64
    int t = kc >> 2;
    int cib = (kc & 3) * 64;
    int shift = t - 1;
    int c2 = coordv + shift;
    { // A: 64 rows x 64ch, 16 ch (2 x uint4) per thread
      const unsigned short* asrc =
          xbase + ((size_t)(n + shift * cstride)) * Cn + cib + akp * 16;
      uint4 av0 = (c2 >= 0 && c2 < 16) ? ((const uint4*)asrc)[0] : (uint4){0, 0, 0, 0};
      uint4 av1 = (c2 >= 0 && c2 < 16) ? ((const uint4*)asrc)[1] : (uint4){0, 0, 0, 0};
      uint4* ad = (uint4*)(Al + arow * 72 + akp * 16);
      ad[0] = av0; ad[1] = av1;
    }
    { // B: 256 rows x 64ch, rows tid>>2 + 64i, 16 ch per thread per row
      #pragma unroll
      for (int i = 0; i < 4; i++) {
        int row = (tid >> 2) + 64 * i;
        const unsigned short* bsrc =
            wbase + ((size_t)(t * 256 + row)) * 256 + cib + akp * 16;
        uint4* bd = (uint4*)(Bl + row * 72 + akp * 16);
        bd[0] = ((const uint4*)bsrc)[0];
        bd[1] = ((const uint4*)bsrc)[1];
      }
    }
    __syncthreads();
    int arowf = wave * 16 + l15;
    #pragma unroll
    for (int kk = 0; kk < 2; kk++) {
      short8 af = *(const short8*)(Al + arowf * 72 + kk * 32 + l4 * 8);
      #pragma unroll
      for (int ct = 0; ct < 16; ct++) {
        int brow = ct * 16 + l15;
        short8 bf = *(const short8*)(Bl + brow * 72 + kk * 32 + l4 * 8);
        acc[ct] = mfma16(af, bf, acc[ct]);
      }
    }
    __syncthreads();
  }

  // bias + channel-LN per row (rows r = l4*4+i, cols ct*16+l15)
  float bv_[16], scv[16], lbv[16];
  #pragma unroll
  for (int ct = 0; ct < 16; ct++) {
    int c = ct * 16 + l15;
    bv_[ct] = bias[c]; scv[ct] = lsc[c]; lbv[ct] = lbi[c];
  }
  unsigned short* ob = qkv + ((size_t)(tensor * Bn + b) * Nn) * Cn;
  #pragma unroll
  for (int i = 0; i < 4; i++) {
    float s = 0.f, s2 = 0.f;
    #pragma unroll
    for (int ct = 0; ct < 16; ct++) {
      float v = acc[ct][i] + bv_[ct];
      s += v; s2 += v * v;
    }
    s  += __shfl_xor(s, 1);  s  += __shfl_xor(s, 2);
    s  += __shfl_xor(s, 4);  s  += __shfl_xor(s, 8);
    s2 += __shfl_xor(s2, 1); s2 += __shfl_xor(s2, 2);
    s2 += __shfl_xor(s2, 4); s2 += __shfl_xor(s2, 8);
    float mean = s * (1.f / 256.f);
    float var  = s2 * (1.f / 256.f) - mean * mean;
    float inv  = rsqrtf(var + 1e-5f);
    int nn = n0 + wave * 16 + l4 * 4 + i;
    unsigned short* orow = ob + (size_t)nn * Cn;
    #pragma unroll
    for (int ct = 0; ct < 16; ct++) {
      float v = acc[ct][i] + bv_[ct];
      orow[ct * 16 + l15] = f2bf((v - mean) * inv * scv[ct] + lbv[ct]);
    }
  }
}

// ---------------------------------------------------------------------------
// 5) Flash attention partials — R16 config (KVB=64, grid dim3(64,2,4),
//    256 thr, 2 barriers/step, bf16 Opart) + defer-max: skip the O-rescale
//    when no lane's max grew (al==1 exactly -> skip is bit-exact).
// ---------------------------------------------------------------------------
__global__ __launch_bounds__(256, 2) void flash_kernel(
    const unsigned short* __restrict__ qkv, unsigned short* __restrict__ Opart,
    float* __restrict__ ml) {
  __shared__ unsigned short Ks[KVB][264];
  __shared__ unsigned short Vt[256][72];
  __shared__ unsigned short Pl[4][16][72];
  const int tid = threadIdx.x, lane = tid & 63, wave = tid >> 6;
  const int l15 = lane & 15, l4 = lane >> 4;
  const int qt = blockIdx.x, b = blockIdx.y, sp = blockIdx.z;
  const unsigned short* Q = qkv + (size_t)(0 * Bn + b) * Nn * Cn;
  const unsigned short* K = qkv + (size_t)(1 * Bn + b) * Nn * Cn;
  const unsigned short* V = qkv + (size_t)(2 * Bn + b) * Nn * Cn;
  const int q0 = qt * 64 + wave * 16;

  short8 qf[8];
  {
    const unsigned short* qp = Q + (size_t)(q0 + l15) * Cn + l4 * 8;
    #pragma unroll
    for (int kk = 0; kk < 8; kk++) qf[kk] = *(const short8*)(qp + kk * 32);
  }
  f32x4 acc_o[16];
  #pragma unroll
  for (int i = 0; i < 16; i++) acc_o[i] = (f32x4){0.f, 0.f, 0.f, 0.f};
  float m_r[4], l_r[4];
  #pragma unroll
  for (int i = 0; i < 4; i++) { m_r[i] = -1e30f; l_r[i] = 0.f; }

  const int kvbase = sp * (Nn / SPLIT);
  const float scl = 0.0625f;                  // 1/sqrt(256)

  for (int step = 0; step < NSTEP; step++) {
    int kv0 = kvbase + step * KVB;
    { // stage K: 64 rows, 4 threads/row, contiguous 128B (8 x uint4) each
      int r = tid >> 2, cp = tid & 3;
      const unsigned short* src = K + (size_t)(kv0 + r) * Cn + cp * 64;
      uint4* dst = (uint4*)&Ks[r][cp * 64];
      #pragma unroll
      for (int i = 0; i < 8; i++) dst[i] = ((const uint4*)src)[i];
    }
    { // stage V transposed: 2 k-rows x 32 ch per thread, packed b32 writes
      int rp = (tid & 31) * 2, ch = (tid >> 5) * 32;
      const unsigned short* s0p = V + (size_t)(kv0 + rp) * Cn + ch;
      const unsigned short* s1p = s0p + Cn;
      union { uint4 v[4]; unsigned short u[32]; } r0, r1;
      #pragma unroll
      for (int i = 0; i < 4; i++) {
        r0.v[i] = ((const uint4*)s0p)[i];
        r1.v[i] = ((const uint4*)s1p)[i];
      }
      #pragma unroll
      for (int j = 0; j < 32; j++) {
        unsigned int pack = (unsigned int)r0.u[j] | ((unsigned int)r1.u[j] << 16);
        *(unsigned int*)&Vt[ch + j][rp] = pack;
      }
    }
    __syncthreads();

    // S = Q K^T over four 16-col tiles
    f32x4 s[4];
    #pragma unroll
    for (int t = 0; t < 4; t++) s[t] = (f32x4){0.f, 0.f, 0.f, 0.f};
    #pragma unroll
    for (int kk = 0; kk < 8; kk++) {
      #pragma unroll
      for (int t = 0; t < 4; t++) {
        short8 bt = *(const short8*)&Ks[t * 16 + l15][kk * 32 + l4 * 8];
        s[t] = mfma16(qf[kk], bt, s[t]);
      }
    }

    // online softmax (rows = l4*4+i, 64 cols = 4 subtiles x 16 lanes)
    float p[4][4], al[4];
    #pragma unroll
    for (int i = 0; i < 4; i++) {
      float a0 = s[0][i] * scl, a1 = s[1][i] * scl;
      float a2 = s[2][i] * scl, a3 = s[3][i] * scl;
      float mt = fmaxf(fmaxf(a0, a1), fmaxf(a2, a3));
      mt = fmaxf(mt, __shfl_xor(mt, 1));
      mt = fmaxf(mt, __shfl_xor(mt, 2));
      mt = fmaxf(mt, __shfl_xor(mt, 4));
      mt = fmaxf(mt, __shfl_xor(mt, 8));
      float mn = fmaxf(m_r[i], mt);
      float a = __expf(m_r[i] - mn);
      m_r[i] = mn; al[i] = a;
      p[0][i] = __expf(a0 - mn);
      p[1][i] = __expf(a1 - mn);
      p[2][i] = __expf(a2 - mn);
      p[3][i] = __expf(a3 - mn);
      float r = (p[0][i] + p[1][i]) + (p[2][i] + p[3][i]);
      r += __shfl_xor(r, 1); r += __shfl_xor(r, 2);
      r += __shfl_xor(r, 4); r += __shfl_xor(r, 8);
      l_r[i] = l_r[i] * a + r;
    }
    // P -> LDS (bf16) in A-fragment layout
    #pragma unroll
    for (int i = 0; i < 4; i++) {
      int row = l4 * 4 + i;
      #pragma unroll
      for (int t = 0; t < 4; t++)
        Pl[wave][row][t * 16 + l15] = f2bf(p[t][i]);
    }
    // rescale O (defer-max: skip when no lane's max grew; al==1 exactly then)
    bool grew = (al[0] != 1.f) | (al[1] != 1.f) | (al[2] != 1.f) | (al[3] != 1.f);
    if (__any(grew)) {
      #pragma unroll
      for (int ct = 0; ct < 16; ct++)
        #pragma unroll
        for (int i = 0; i < 4; i++) acc_o[ct][i] *= al[i];
    }

    // PV over two K=32 slices
    short8 pf0 = *(const short8*)&Pl[wave][l15][l4 * 8];
    short8 pf1 = *(const short8*)&Pl[wave][l15][32 + l4 * 8];
    #pragma unroll
    for (int ct = 0; ct < 16; ct++) {
      short8 vf0 = *(const short8*)&Vt[ct * 16 + l15][l4 * 8];
      short8 vf1 = *(const short8*)&Vt[ct * 16 + l15][32 + l4 * 8];
      acc_o[ct] = mfma16(pf0, vf0, acc_o[ct]);
      acc_o[ct] = mfma16(pf1, vf1, acc_o[ct]);
    }
    __syncthreads();
  }

  // write unnormalized partials (bf16) + (m,l)
  unsigned short* ob = Opart + ((size_t)(sp * Bn + b) * Nn) * Cn;
  #pragma unroll
  for (int ct = 0; ct < 16; ct++) {
    int c = ct * 16 + l15;
    #pragma unroll
    for (int i = 0; i < 4; i++) {
      int nn = q0 + l4 * 4 + i;
      ob[(size_t)nn * Cn + c] = f2bf(acc_o[ct][i]);
    }
  }
  if (l15 == 0) {
    #pragma unroll
    for (int i = 0; i < 4; i++) {
      int nn = q0 + l4 * 4 + i;
      size_t mb = (((size_t)sp * Bn + b) * Nn + nn) * 2;
      ml[mb]     = m_r[i];
      ml[mb + 1] = l_r[i];
    }
  }
}

// ---------------------------------------------------------------------------
// 6) Combine splits + out = gamma*att + xgT (bf16 residual, fused at T-fill),
//    transposed to [b][c][n] via LDS.
// ---------------------------------------------------------------------------
__global__ __launch_bounds__(256) void combine_kernel(
    const unsigned short* __restrict__ Opart, const float* __restrict__ ml,
    const unsigned short* __restrict__ xgT, const float* __restrict__ gamma,
    float* __restrict__ out) {
  __shared__ float T[256][17];
  const int tid = threadIdx.x;
  const int n0 = blockIdx.x * 16;
  const int b = blockIdx.y;
  const float g = gamma[0];
  for (int r = 0; r < 16; r++) {
    int n = n0 + r;
    float msp[SPLIT], lsp[SPLIT];
    float mm = -1e30f;
    #pragma unroll
    for (int s = 0; s < SPLIT; s++) {
      size_t mb = (((size_t)s * Bn + b) * Nn + n) * 2;
      msp[s] = ml[mb]; lsp[s] = ml[mb + 1];
      mm = fmaxf(mm, msp[s]);
    }
    float denom = 0.f, w[SPLIT];
    #pragma unroll
    for (int s = 0; s < SPLIT; s++) { w[s] = __expf(msp[s] - mm); denom += w[s] * lsp[s]; }
    float inv = 1.f / denom;
    float acc = 0.f;
    #pragma unroll
    for (int s = 0; s < SPLIT; s++)
      acc += w[s] * bf2f(Opart[(((size_t)s * Bn + b) * Nn + n) * Cn + tid]);
    float res = bf2f(xgT[((size_t)(b * Nn + n)) * Cn + tid]);
    T[tid][r] = g * acc * inv + res;
  }
  __syncthreads();
  const int c = tid;
  float4* op = (float4*)(out + ((size_t)(b * Cn + c)) * Nn + n0);
  #pragma unroll
  for (int r4 = 0; r4 < 4; r4++) {
    float4 vv;
    vv.x = T[c][r4 * 4 + 0];
    vv.y = T[c][r4 * 4 + 1];
    vv.z = T[c][r4 * 4 + 2];
    vv.w = T[c][r4 * 4 + 3];
    op[r4] = vv;
  }
}

// ---------------------------------------------------------------------------
extern "C" void kernel_launch(void* const* d_in, const int* in_sizes, int n_in,
                              void* d_out, int out_size, void* d_ws, size_t ws_size,
                              hipStream_t stream) {
  const float* x   = (const float*)d_in[0];
  const float* w1  = (const float*)d_in[1];
  const float* b1  = (const float*)d_in[2];
  const float* w2i = (const float*)d_in[3];
  const float* b2  = (const float*)d_in[4];
  const float* w3  = (const float*)d_in[5];
  const float* b3  = (const float*)d_in[6];
  const float* w4  = (const float*)d_in[7];
  const float* b4  = (const float*)d_in[8];
  const float* wq  = (const float*)d_in[9];
  const float* bq  = (const float*)d_in[10];
  const float* wk  = (const float*)d_in[11];
  const float* bk  = (const float*)d_in[12];
  const float* wv  = (const float*)d_in[13];
  const float* bv  = (const float*)d_in[14];
  const float* qs  = (const float*)d_in[15];
  const float* qb  = (const float*)d_in[16];
  const float* ks  = (const float*)d_in[17];
  const float* kb  = (const float*)d_in[18];
  const float* vs  = (const float*)d_in[19];
  const float* vb  = (const float*)d_in[20];
  const float* gamma = (const float*)d_in[21];
  float* out = (float*)d_out;

  char* ws = (char*)d_ws;
  unsigned short* xgT   = (unsigned short*)(ws + 0);         //  4.19 MB
  unsigned short* w2b   = (unsigned short*)(ws + 4194304);   //  1.18 MB
  unsigned short* qkv   = (unsigned short*)(ws + 5373952);   // 12.58 MB
  unsigned short* Opart = (unsigned short*)(ws + 17956864);  // 16.78 MB (bf16, SPLIT=4)
  float* ml             = (float*)(ws + 34734080);           //  0.26 MB (end 35.0MB)

  prep_w_kernel<<<dim3(2304), dim3(256), 0, stream>>>(wq, wk, wv, w2b);
  gated_kernel<<<dim3(64, 4, 2), dim3(256), 0, stream>>>(
      x, w1, b1, w2i, b2, w3, b3, w4, b4, xgT);
  qkvconv_ln_kernel<<<dim3(64, 2, 3), dim3(256), 0, stream>>>(
      xgT, w2b, bq, bk, bv, qs, qb, ks, kb, vs, vb, qkv);
  flash_kernel<<<dim3(64, 2, SPLIT), dim3(256), 0, stream>>>(qkv, Opart, ml);
  combine_kernel<<<dim3(256, 2), dim3(256), 0, stream>>>(Opart, ml, xgT, gamma, out);
}

// Round 18
// 154.519 us; speedup vs baseline: 1.1711x; 1.0264x over previous
//
#include <hip/hip_runtime.h>

// Problem constants
#define Bn 2
#define Cn 256
#define Nn 4096
#define SPLIT 4
#define KVB 64
#define NSTEP ((Nn / SPLIT) / KVB)

typedef __attribute__((ext_vector_type(8))) short short8;
typedef __attribute__((ext_vector_type(4))) float f32x4;

__device__ __forceinline__ unsigned short f2bf(float f) {
  union { float f; unsigned int u; } v; v.f = f;
  unsigned int r = (v.u + 0x7FFFu + ((v.u >> 16) & 1u)) >> 16;
  return (unsigned short)r;
}
__device__ __forceinline__ float bf2f(unsigned short u) {
  union { unsigned int i; float f; } v; v.i = ((unsigned int)u) << 16; return v.f;
}

__device__ __forceinline__ f32x4 mfma16(short8 a, short8 b, f32x4 c) {
  return __builtin_amdgcn_mfma_f32_16x16x32_bf16(a, b, c, 0, 0, 0);
}

// ---------------------------------------------------------------------------
// 1) Transpose conv weights [co][ci][t] -> bf16 w2[tensor][t][co][ci]
// ---------------------------------------------------------------------------
__global__ void prep_w_kernel(const float* __restrict__ wq,
                              const float* __restrict__ wk,
                              const float* __restrict__ wv,
                              unsigned short* __restrict__ w2) {
  int idx = blockIdx.x * 256 + threadIdx.x;           // 3*3*256*256 = 589824
  int tensor = idx / 196608;
  int rem = idx % 196608;
  int t  = rem >> 16;
  int co = (rem >> 8) & 255;
  int ci = rem & 255;
  const float* w = (tensor == 0) ? wq : (tensor == 1) ? wk : wv;
  w2[idx] = f2bf(w[(co * 256 + ci) * 3 + t]);
}

// ---------------------------------------------------------------------------
// 2) Gated channel-split 1x1x1 convs + SiLU.  Writes ONLY xgT bf16 [b][n][c]
//    (fp32 xg eliminated; residual is added from xgT in combine).
// ---------------------------------------------------------------------------
__global__ __launch_bounds__(256) void gated_kernel(
    const float* __restrict__ x,
    const float* __restrict__ w1, const float* __restrict__ b1,
    const float* __restrict__ w2, const float* __restrict__ b2,
    const float* __restrict__ w3, const float* __restrict__ b3,
    const float* __restrict__ w4, const float* __restrict__ b4,
    unsigned short* __restrict__ xgT) {
  __shared__ float Wl[64][65];
  __shared__ float Xl[64][65];
  __shared__ unsigned short Yl[64][72];
  const int tid = threadIdx.x;
  const int n0 = blockIdx.x * 64;
  const int q  = blockIdx.y;
  const int b  = blockIdx.z;
  const float* wsel = (q == 0) ? w1 : (q == 1) ? w2 : (q == 2) ? w3 : w4;
  const float* bsel = (q == 0) ? b1 : (q == 1) ? b2 : (q == 2) ? b3 : b4;

  #pragma unroll
  for (int it = 0; it < 4; it++) {
    int i = (tid + it * 256) * 4;
    float4 v = *(const float4*)(wsel + i);
    int co = i >> 6, ci = i & 63;
    Wl[co][ci] = v.x; Wl[co][ci + 1] = v.y; Wl[co][ci + 2] = v.z; Wl[co][ci + 3] = v.w;
  }
  {
    int ci = tid >> 2, part = tid & 3;
    const float* src = x + ((size_t)(b * Cn + q * 64 + ci)) * Nn + n0 + part * 16;
    #pragma unroll
    for (int j = 0; j < 4; j++) {
      float4 v = ((const float4*)src)[j];
      float* dst = &Xl[ci][part * 16 + j * 4];
      dst[0] = v.x; dst[1] = v.y; dst[2] = v.z; dst[3] = v.w;
    }
  }
  __syncthreads();
  const int co = tid >> 2, npart = tid & 3;
  float acc[16];
  {
    float bias = bsel[co];
    #pragma unroll
    for (int j = 0; j < 16; j++) acc[j] = bias;
  }
  for (int ci = 0; ci < 64; ci++) {
    float wv_ = Wl[co][ci];
    const float* xr = &Xl[ci][npart * 16];
    #pragma unroll
    for (int j = 0; j < 16; j++) acc[j] += wv_ * xr[j];
  }
  #pragma unroll
  for (int j = 0; j < 16; j++) {
    float v = acc[j];
    float s = v / (1.f + __expf(-v));   // SiLU
    Yl[npart * 16 + j][co] = f2bf(s);
  }
  __syncthreads();
  { // transpose-out: 4 threads per row, 16 channels each -> full 64x64 tile
    int r = tid >> 2, cp = tid & 3;
    union { unsigned short u[16]; uint4 v[2]; } pk;
    #pragma unroll
    for (int j = 0; j < 16; j++) pk.u[j] = Yl[r][cp * 16 + j];
    uint4* dst = (uint4*)(xgT + ((size_t)(b * Nn + n0 + r)) * Cn + q * 64 + cp * 16);
    dst[0] = pk.v[0];
    dst[1] = pk.v[1];
  }
}

// ---------------------------------------------------------------------------
// 3) QKV directional convs + fused channel LayerNorm.  K-chunk = 64
//    (12 iterations, 24 barriers), padded LDS stride 72 (9 slots -> 2-way).
// ---------------------------------------------------------------------------
__global__ __launch_bounds__(256) void qkvconv_ln_kernel(
    const unsigned short* __restrict__ xgT, const unsigned short* __restrict__ w2,
    const float* __restrict__ bq, const float* __restrict__ bk,
    const float* __restrict__ bv,
    const float* __restrict__ qs, const float* __restrict__ qb,
    const float* __restrict__ ks, const float* __restrict__ kb,
    const float* __restrict__ vs, const float* __restrict__ vb,
    unsigned short* __restrict__ qkv) {
  __shared__ unsigned short Al[64 * 72];
  __shared__ unsigned short Bl[256 * 72];
  const int tid = threadIdx.x;
  const int lane = tid & 63, wave = tid >> 6;
  const int l15 = lane & 15, l4 = lane >> 4;
  const int n0  = blockIdx.x * 64;
  const int b = blockIdx.y;
  const int tensor = blockIdx.z;
  const int cstride = (tensor == 0) ? 16 : (tensor == 1) ? 1 : 256;   // H, W, D
  const float* bias = (tensor == 0) ? bq : (tensor == 1) ? bk : bv;
  const float* lsc = (tensor == 0) ? qs : (tensor == 1) ? ks : vs;
  const float* lbi = (tensor == 0) ? qb : (tensor == 1) ? kb : vb;
  const unsigned short* wbase = w2 + (size_t)tensor * 196608;
  const unsigned short* xbase = xgT + (size_t)b * Nn * Cn;

  f32x4 acc[16];
  #pragma unroll
  for (int i = 0; i < 16; i++) acc[i] = (f32x4){0.f, 0.f, 0.f, 0.f};

  const int arow = tid >> 2, akp = tid & 3;     // A staging: row, 16-ch chunk
  const int n = n0 + arow;
  const int coordv = (n / cstride) & 15;        // coordinate along conv axis

  for (int kc = 0; kc < 12; kc++) {             // 12 chunks of K=64
    int t = kc >> 2;
    int cib = (kc & 3) * 64;
    int shift = t - 1;
    int c2 = coordv + shift;
    { // A: 64 rows x 64ch, 16 ch (2 x uint4) per thread
      const unsigned short* asrc =
          xbase + ((size_t)(n + shift * cstride)) * Cn + cib + akp * 16;
      uint4 av0 = (c2 >= 0 && c2 < 16) ? ((const uint4*)asrc)[0] : (uint4){0, 0, 0, 0};
      uint4 av1 = (c2 >= 0 && c2 < 16) ? ((const uint4*)asrc)[1] : (uint4){0, 0, 0, 0};
      uint4* ad = (uint4*)(Al + arow * 72 + akp * 16);
      ad[0] = av0; ad[1] = av1;
    }
    { // B: 256 rows x 64ch, rows tid>>2 + 64i, 16 ch per thread per row
      #pragma unroll
      for (int i = 0; i < 4; i++) {
        int row = (tid >> 2) + 64 * i;
        const unsigned short* bsrc =
            wbase + ((size_t)(t * 256 + row)) * 256 + cib + akp * 16;
        uint4* bd = (uint4*)(Bl + row * 72 + akp * 16);
        bd[0] = ((const uint4*)bsrc)[0];
        bd[1] = ((const uint4*)bsrc)[1];
      }
    }
    __syncthreads();
    int arowf = wave * 16 + l15;
    #pragma unroll
    for (int kk = 0; kk < 2; kk++) {
      short8 af = *(const short8*)(Al + arowf * 72 + kk * 32 + l4 * 8);
      #pragma unroll
      for (int ct = 0; ct < 16; ct++) {
        int brow = ct * 16 + l15;
        short8 bf = *(const short8*)(Bl + brow * 72 + kk * 32 + l4 * 8);
        acc[ct] = mfma16(af, bf, acc[ct]);
      }
    }
    __syncthreads();
  }

  // bias + channel-LN per row (rows r = l4*4+i, cols ct*16+l15)
  float bv_[16], scv[16], lbv[16];
  #pragma unroll
  for (int ct = 0; ct < 16; ct++) {
    int c = ct * 16 + l15;
    bv_[ct] = bias[c]; scv[ct] = lsc[c]; lbv[ct] = lbi[c];
  }
  unsigned short* ob = qkv + ((size_t)(tensor * Bn + b) * Nn) * Cn;
  #pragma unroll
  for (int i = 0; i < 4; i++) {
    float s = 0.f, s2 = 0.f;
    #pragma unroll
    for (int ct = 0; ct < 16; ct++) {
      float v = acc[ct][i] + bv_[ct];
      s += v; s2 += v * v;
    }
    s  += __shfl_xor(s, 1);  s  += __shfl_xor(s, 2);
    s  += __shfl_xor(s, 4);  s  += __shfl_xor(s, 8);
    s2 += __shfl_xor(s2, 1); s2 += __shfl_xor(s2, 2);
    s2 += __shfl_xor(s2, 4); s2 += __shfl_xor(s2, 8);
    float mean = s * (1.f / 256.f);
    float var  = s2 * (1.f / 256.f) - mean * mean;
    float inv  = rsqrtf(var + 1e-5f);
    int nn = n0 + wave * 16 + l4 * 4 + i;
    unsigned short* orow = ob + (size_t)nn * Cn;
    #pragma unroll
    for (int ct = 0; ct < 16; ct++) {
      float v = acc[ct][i] + bv_[ct];
      orow[ct * 16 + l15] = f2bf((v - mean) * inv * scv[ct] + lbv[ct]);
    }
  }
}

// ---------------------------------------------------------------------------
// 5) Flash attention partials — R16 configuration exactly (KVB=64, grid
//    dim3(64,2,4), 256 thr, 2 barriers/step, bf16 Opart, unconditional
//    O-rescale).  Defer-max reverted: it cost +3.6us (R17 measurement).
// ---------------------------------------------------------------------------
__global__ __launch_bounds__(256, 2) void flash_kernel(
    const unsigned short* __restrict__ qkv, unsigned short* __restrict__ Opart,
    float* __restrict__ ml) {
  __shared__ unsigned short Ks[KVB][264];
  __shared__ unsigned short Vt[256][72];
  __shared__ unsigned short Pl[4][16][72];
  const int tid = threadIdx.x, lane = tid & 63, wave = tid >> 6;
  const int l15 = lane & 15, l4 = lane >> 4;
  const int qt = blockIdx.x, b = blockIdx.y, sp = blockIdx.z;
  const unsigned short* Q = qkv + (size_t)(0 * Bn + b) * Nn * Cn;
  const unsigned short* K = qkv + (size_t)(1 * Bn + b) * Nn * Cn;
  const unsigned short* V = qkv + (size_t)(2 * Bn + b) * Nn * Cn;
  const int q0 = qt * 64 + wave * 16;

  short8 qf[8];
  {
    const unsigned short* qp = Q + (size_t)(q0 + l15) * Cn + l4 * 8;
    #pragma unroll
    for (int kk = 0; kk < 8; kk++) qf[kk] = *(const short8*)(qp + kk * 32);
  }
  f32x4 acc_o[16];
  #pragma unroll
  for (int i = 0; i < 16; i++) acc_o[i] = (f32x4){0.f, 0.f, 0.f, 0.f};
  float m_r[4], l_r[4];
  #pragma unroll
  for (int i = 0; i < 4; i++) { m_r[i] = -1e30f; l_r[i] = 0.f; }

  const int kvbase = sp * (Nn / SPLIT);
  const float scl = 0.0625f;                  // 1/sqrt(256)

  for (int step = 0; step < NSTEP; step++) {
    int kv0 = kvbase + step * KVB;
    { // stage K: 64 rows, 4 threads/row, contiguous 128B (8 x uint4) each
      int r = tid >> 2, cp = tid & 3;
      const unsigned short* src = K + (size_t)(kv0 + r) * Cn + cp * 64;
      uint4* dst = (uint4*)&Ks[r][cp * 64];
      #pragma unroll
      for (int i = 0; i < 8; i++) dst[i] = ((const uint4*)src)[i];
    }
    { // stage V transposed: 2 k-rows x 32 ch per thread, packed b32 writes
      int rp = (tid & 31) * 2, ch = (tid >> 5) * 32;
      const unsigned short* s0p = V + (size_t)(kv0 + rp) * Cn + ch;
      const unsigned short* s1p = s0p + Cn;
      union { uint4 v[4]; unsigned short u[32]; } r0, r1;
      #pragma unroll
      for (int i = 0; i < 4; i++) {
        r0.v[i] = ((const uint4*)s0p)[i];
        r1.v[i] = ((const uint4*)s1p)[i];
      }
      #pragma unroll
      for (int j = 0; j < 32; j++) {
        unsigned int pack = (unsigned int)r0.u[j] | ((unsigned int)r1.u[j] << 16);
        *(unsigned int*)&Vt[ch + j][rp] = pack;
      }
    }
    __syncthreads();

    // S = Q K^T over four 16-col tiles
    f32x4 s[4];
    #pragma unroll
    for (int t = 0; t < 4; t++) s[t] = (f32x4){0.f, 0.f, 0.f, 0.f};
    #pragma unroll
    for (int kk = 0; kk < 8; kk++) {
      #pragma unroll
      for (int t = 0; t < 4; t++) {
        short8 bt = *(const short8*)&Ks[t * 16 + l15][kk * 32 + l4 * 8];
        s[t] = mfma16(qf[kk], bt, s[t]);
      }
    }

    // online softmax (rows = l4*4+i, 64 cols = 4 subtiles x 16 lanes)
    float p[4][4], al[4];
    #pragma unroll
    for (int i = 0; i < 4; i++) {
      float a0 = s[0][i] * scl, a1 = s[1][i] * scl;
      float a2 = s[2][i] * scl, a3 = s[3][i] * scl;
      float mt = fmaxf(fmaxf(a0, a1), fmaxf(a2, a3));
      mt = fmaxf(mt, __shfl_xor(mt, 1));
      mt = fmaxf(mt, __shfl_xor(mt, 2));
      mt = fmaxf(mt, __shfl_xor(mt, 4));
      mt = fmaxf(mt, __shfl_xor(mt, 8));
      float mn = fmaxf(m_r[i], mt);
      float a = __expf(m_r[i] - mn);
      m_r[i] = mn; al[i] = a;
      p[0][i] = __expf(a0 - mn);
      p[1][i] = __expf(a1 - mn);
      p[2][i] = __expf(a2 - mn);
      p[3][i] = __expf(a3 - mn);
      float r = (p[0][i] + p[1][i]) + (p[2][i] + p[3][i]);
      r += __shfl_xor(r, 1); r += __shfl_xor(r, 2);
      r += __shfl_xor(r, 4); r += __shfl_xor(r, 8);
      l_r[i] = l_r[i] * a + r;
    }
    // P -> LDS (bf16) in A-fragment layout
    #pragma unroll
    for (int i = 0; i < 4; i++) {
      int row = l4 * 4 + i;
      #pragma unroll
      for (int t = 0; t < 4; t++)
        Pl[wave][row][t * 16 + l15] = f2bf(p[t][i]);
    }
    // rescale O
    #pragma unroll
    for (int ct = 0; ct < 16; ct++)
      #pragma unroll
      for (int i = 0; i < 4; i++) acc_o[ct][i] *= al[i];

    // PV over two K=32 slices
    short8 pf0 = *(const short8*)&Pl[wave][l15][l4 * 8];
    short8 pf1 = *(const short8*)&Pl[wave][l15][32 + l4 * 8];
    #pragma unroll
    for (int ct = 0; ct < 16; ct++) {
      short8 vf0 = *(const short8*)&Vt[ct * 16 + l15][l4 * 8];
      short8 vf1 = *(const short8*)&Vt[ct * 16 + l15][32 + l4 * 8];
      acc_o[ct] = mfma16(pf0, vf0, acc_o[ct]);
      acc_o[ct] = mfma16(pf1, vf1, acc_o[ct]);
    }
    __syncthreads();
  }

  // write unnormalized partials (bf16) + (m,l)
  unsigned short* ob = Opart + ((size_t)(sp * Bn + b) * Nn) * Cn;
  #pragma unroll
  for (int ct = 0; ct < 16; ct++) {
    int c = ct * 16 + l15;
    #pragma unroll
    for (int i = 0; i < 4; i++) {
      int nn = q0 + l4 * 4 + i;
      ob[(size_t)nn * Cn + c] = f2bf(acc_o[ct][i]);
    }
  }
  if (l15 == 0) {
    #pragma unroll
    for (int i = 0; i < 4; i++) {
      int nn = q0 + l4 * 4 + i;
      size_t mb = (((size_t)sp * Bn + b) * Nn + nn) * 2;
      ml[mb]     = m_r[i];
      ml[mb + 1] = l_r[i];
    }
  }
}

// ---------------------------------------------------------------------------
// 6) Combine splits + out = gamma*att + xgT (bf16 residual, fused at T-fill),
//    transposed to [b][c][n] via LDS.
// ---------------------------------------------------------------------------
__global__ __launch_bounds__(256) void combine_kernel(
    const unsigned short* __restrict__ Opart, const float* __restrict__ ml,
    const unsigned short* __restrict__ xgT, const float* __restrict__ gamma,
    float* __restrict__ out) {
  __shared__ float T[256][17];
  const int tid = threadIdx.x;
  const int n0 = blockIdx.x * 16;
  const int b = blockIdx.y;
  const float g = gamma[0];
  for (int r = 0; r < 16; r++) {
    int n = n0 + r;
    float msp[SPLIT], lsp[SPLIT];
    float mm = -1e30f;
    #pragma unroll
    for (int s = 0; s < SPLIT; s++) {
      size_t mb = (((size_t)s * Bn + b) * Nn + n) * 2;
      msp[s] = ml[mb]; lsp[s] = ml[mb + 1];
      mm = fmaxf(mm, msp[s]);
    }
    float denom = 0.f, w[SPLIT];
    #pragma unroll
    for (int s = 0; s < SPLIT; s++) { w[s] = __expf(msp[s] - mm); denom += w[s] * lsp[s]; }
    float inv = 1.f / denom;
    float acc = 0.f;
    #pragma unroll
    for (int s = 0; s < SPLIT; s++)
      acc += w[s] * bf2f(Opart[(((size_t)s * Bn + b) * Nn + n) * Cn + tid]);
    float res = bf2f(xgT[((size_t)(b * Nn + n)) * Cn + tid]);
    T[tid][r] = g * acc * inv + res;
  }
  __syncthreads();
  const int c = tid;
  float4* op = (float4*)(out + ((size_t)(b * Cn + c)) * Nn + n0);
  #pragma unroll
  for (int r4 = 0; r4 < 4; r4++) {
    float4 vv;
    vv.x = T[c][r4 * 4 + 0];
    vv.y = T[c][r4 * 4 + 1];
    vv.z = T[c][r4 * 4 + 2];
    vv.w = T[c][r4 * 4 + 3];
    op[r4] = vv;
  }
}

// ---------------------------------------------------------------------------
extern "C" void kernel_launch(void* const* d_in, const int* in_sizes, int n_in,
                              void* d_out, int out_size, void* d_ws, size_t ws_size,
                              hipStream_t stream) {
  const float* x   = (const float*)d_in[0];
  const float* w1  = (const float*)d_in[1];
  const float* b1  = (const float*)d_in[2];
  const float* w2i = (const float*)d_in[3];
  const float* b2  = (const float*)d_in[4];
  const float* w3  = (const float*)d_in[5];
  const float* b3  = (const float*)d_in[6];
  const float* w4  = (const float*)d_in[7];
  const float* b4  = (const float*)d_in[8];
  const float* wq  = (const float*)d_in[9];
  const float* bq  = (const float*)d_in[10];
  const float* wk  = (const float*)d_in[11];
  const float* bk  = (const float*)d_in[12];
  const float* wv  = (const float*)d_in[13];
  const float* bv  = (const float*)d_in[14];
  const float* qs  = (const float*)d_in[15];
  const float* qb  = (const float*)d_in[16];
  const float* ks  = (const float*)d_in[17];
  const float* kb  = (const float*)d_in[18];
  const float* vs  = (const float*)d_in[19];
  const float* vb  = (const float*)d_in[20];
  const float* gamma = (const float*)d_in[21];
  float* out = (float*)d_out;

  char* ws = (char*)d_ws;
  unsigned short* xgT   = (unsigned short*)(ws + 0);         //  4.19 MB
  unsigned short* w2b   = (unsigned short*)(ws + 4194304);   //  1.18 MB
  unsigned short* qkv   = (unsigned short*)(ws + 5373952);   // 12.58 MB
  unsigned short* Opart = (unsigned short*)(ws + 17956864);  // 16.78 MB (bf16, SPLIT=4)
  float* ml             = (float*)(ws + 34734080);           //  0.26 MB (end 35.0MB)

  prep_w_kernel<<<dim3(2304), dim3(256), 0, stream>>>(wq, wk, wv, w2b);
  gated_kernel<<<dim3(64, 4, 2), dim3(256), 0, stream>>>(
      x, w1, b1, w2i, b2, w3, b3, w4, b4, xgT);
  qkvconv_ln_kernel<<<dim3(64, 2, 3), dim3(256), 0, stream>>>(
      xgT, w2b, bq, bk, bv, qs, qb, ks, kb, vs, vb, qkv);
  flash_kernel<<<dim3(64, 2, SPLIT), dim3(256), 0, stream>>>(qkv, Opart, ml);
  combine_kernel<<<dim3(256, 2), dim3(256), 0, stream>>>(Opart, ml, xgT, gamma, out);
}

// Round 19
// 154.071 us; speedup vs baseline: 1.1745x; 1.0029x over previous
//
#include <hip/hip_runtime.h>

// Problem constants
#define Bn 2
#define Cn 256
#define Nn 4096
#define SPLIT 4
#define KVB 64
#define NSTEP ((Nn / SPLIT) / KVB)

typedef __attribute__((ext_vector_type(8))) short short8;
typedef __attribute__((ext_vector_type(4))) float f32x4;

__device__ __forceinline__ unsigned short f2bf(float f) {
  union { float f; unsigned int u; } v; v.f = f;
  unsigned int r = (v.u + 0x7FFFu + ((v.u >> 16) & 1u)) >> 16;
  return (unsigned short)r;
}
__device__ __forceinline__ float bf2f(unsigned short u) {
  union { unsigned int i; float f; } v; v.i = ((unsigned int)u) << 16; return v.f;
}

__device__ __forceinline__ f32x4 mfma16(short8 a, short8 b, f32x4 c) {
  return __builtin_amdgcn_mfma_f32_16x16x32_bf16(a, b, c, 0, 0, 0);
}

// ---------------------------------------------------------------------------
// 1) Transpose conv weights [co][ci][t] -> bf16 w2[tensor][t][co][ci]
// ---------------------------------------------------------------------------
__global__ void prep_w_kernel(const float* __restrict__ wq,
                              const float* __restrict__ wk,
                              const float* __restrict__ wv,
                              unsigned short* __restrict__ w2) {
  int idx = blockIdx.x * 256 + threadIdx.x;           // 3*3*256*256 = 589824
  int tensor = idx / 196608;
  int rem = idx % 196608;
  int t  = rem >> 16;
  int co = (rem >> 8) & 255;
  int ci = rem & 255;
  const float* w = (tensor == 0) ? wq : (tensor == 1) ? wk : wv;
  w2[idx] = f2bf(w[(co * 256 + ci) * 3 + t]);
}

// ---------------------------------------------------------------------------
// 2) Gated channel-split 1x1x1 convs + SiLU.  Writes ONLY xgT bf16 [b][n][c]
// ---------------------------------------------------------------------------
__global__ __launch_bounds__(256) void gated_kernel(
    const float* __restrict__ x,
    const float* __restrict__ w1, const float* __restrict__ b1,
    const float* __restrict__ w2, const float* __restrict__ b2,
    const float* __restrict__ w3, const float* __restrict__ b3,
    const float* __restrict__ w4, const float* __restrict__ b4,
    unsigned short* __restrict__ xgT) {
  __shared__ float Wl[64][65];
  __shared__ float Xl[64][65];
  __shared__ unsigned short Yl[64][72];
  const int tid = threadIdx.x;
  const int n0 = blockIdx.x * 64;
  const int q  = blockIdx.y;
  const int b  = blockIdx.z;
  const float* wsel = (q == 0) ? w1 : (q == 1) ? w2 : (q == 2) ? w3 : w4;
  const float* bsel = (q == 0) ? b1 : (q == 1) ? b2 : (q == 2) ? b3 : b4;

  #pragma unroll
  for (int it = 0; it < 4; it++) {
    int i = (tid + it * 256) * 4;
    float4 v = *(const float4*)(wsel + i);
    int co = i >> 6, ci = i & 63;
    Wl[co][ci] = v.x; Wl[co][ci + 1] = v.y; Wl[co][ci + 2] = v.z; Wl[co][ci + 3] = v.w;
  }
  {
    int ci = tid >> 2, part = tid & 3;
    const float* src = x + ((size_t)(b * Cn + q * 64 + ci)) * Nn + n0 + part * 16;
    #pragma unroll
    for (int j = 0; j < 4; j++) {
      float4 v = ((const float4*)src)[j];
      float* dst = &Xl[ci][part * 16 + j * 4];
      dst[0] = v.x; dst[1] = v.y; dst[2] = v.z; dst[3] = v.w;
    }
  }
  __syncthreads();
  const int co = tid >> 2, npart = tid & 3;
  float acc[16];
  {
    float bias = bsel[co];
    #pragma unroll
    for (int j = 0; j < 16; j++) acc[j] = bias;
  }
  for (int ci = 0; ci < 64; ci++) {
    float wv_ = Wl[co][ci];
    const float* xr = &Xl[ci][npart * 16];
    #pragma unroll
    for (int j = 0; j < 16; j++) acc[j] += wv_ * xr[j];
  }
  #pragma unroll
  for (int j = 0; j < 16; j++) {
    float v = acc[j];
    float s = v / (1.f + __expf(-v));   // SiLU
    Yl[npart * 16 + j][co] = f2bf(s);
  }
  __syncthreads();
  { // transpose-out: 4 threads per row, 16 channels each -> full 64x64 tile
    int r = tid >> 2, cp = tid & 3;
    union { unsigned short u[16]; uint4 v[2]; } pk;
    #pragma unroll
    for (int j = 0; j < 16; j++) pk.u[j] = Yl[r][cp * 16 + j];
    uint4* dst = (uint4*)(xgT + ((size_t)(b * Nn + n0 + r)) * Cn + q * 64 + cp * 16);
    dst[0] = pk.v[0];
    dst[1] = pk.v[1];
  }
}

// ---------------------------------------------------------------------------
// 3) QKV directional convs + fused channel LayerNorm.  M-tile = 32 rows,
//    128 thr / 2 waves, grid (128,2,3) = 768 blocks = exactly 3 blocks/CU
//    (balanced; the 384-block version left half the CUs double-loaded).
//    K-chunk = 64, padded LDS stride 72.
// ---------------------------------------------------------------------------
__global__ __launch_bounds__(128) void qkvconv_ln_kernel(
    const unsigned short* __restrict__ xgT, const unsigned short* __restrict__ w2,
    const float* __restrict__ bq, const float* __restrict__ bk,
    const float* __restrict__ bv,
    const float* __restrict__ qs, const float* __restrict__ qb,
    const float* __restrict__ ks, const float* __restrict__ kb,
    const float* __restrict__ vs, const float* __restrict__ vb,
    unsigned short* __restrict__ qkv) {
  __shared__ unsigned short Al[32 * 72];
  __shared__ unsigned short Bl[256 * 72];
  const int tid = threadIdx.x;
  const int lane = tid & 63, wave = tid >> 6;
  const int l15 = lane & 15, l4 = lane >> 4;
  const int n0  = blockIdx.x * 32;
  const int b = blockIdx.y;
  const int tensor = blockIdx.z;
  const int cstride = (tensor == 0) ? 16 : (tensor == 1) ? 1 : 256;   // H, W, D
  const float* bias = (tensor == 0) ? bq : (tensor == 1) ? bk : bv;
  const float* lsc = (tensor == 0) ? qs : (tensor == 1) ? ks : vs;
  const float* lbi = (tensor == 0) ? qb : (tensor == 1) ? kb : vb;
  const unsigned short* wbase = w2 + (size_t)tensor * 196608;
  const unsigned short* xbase = xgT + (size_t)b * Nn * Cn;

  f32x4 acc[16];
  #pragma unroll
  for (int i = 0; i < 16; i++) acc[i] = (f32x4){0.f, 0.f, 0.f, 0.f};

  const int arow = tid >> 2, akp = tid & 3;     // A staging: row (0..31), 16-ch chunk
  const int n = n0 + arow;
  const int coordv = (n / cstride) & 15;        // coordinate along conv axis

  for (int kc = 0; kc < 12; kc++) {             // 12 chunks of K=64
    int t = kc >> 2;
    int cib = (kc & 3) * 64;
    int shift = t - 1;
    int c2 = coordv + shift;
    { // A: 32 rows x 64ch, 16 ch (2 x uint4) per thread
      const unsigned short* asrc =
          xbase + ((size_t)(n + shift * cstride)) * Cn + cib + akp * 16;
      uint4 av0 = (c2 >= 0 && c2 < 16) ? ((const uint4*)asrc)[0] : (uint4){0, 0, 0, 0};
      uint4 av1 = (c2 >= 0 && c2 < 16) ? ((const uint4*)asrc)[1] : (uint4){0, 0, 0, 0};
      uint4* ad = (uint4*)(Al + arow * 72 + akp * 16);
      ad[0] = av0; ad[1] = av1;
    }
    { // B: 256 rows x 64ch, rows tid>>2 + 32i (i=0..7), 16 ch per thread per row
      #pragma unroll
      for (int i = 0; i < 8; i++) {
        int row = (tid >> 2) + 32 * i;
        const unsigned short* bsrc =
            wbase + ((size_t)(t * 256 + row)) * 256 + cib + akp * 16;
        uint4* bd = (uint4*)(Bl + row * 72 + akp * 16);
        bd[0] = ((const uint4*)bsrc)[0];
        bd[1] = ((const uint4*)bsrc)[1];
      }
    }
    __syncthreads();
    int arowf = wave * 16 + l15;
    #pragma unroll
    for (int kk = 0; kk < 2; kk++) {
      short8 af = *(const short8*)(Al + arowf * 72 + kk * 32 + l4 * 8);
      #pragma unroll
      for (int ct = 0; ct < 16; ct++) {
        int brow = ct * 16 + l15;
        short8 bf = *(const short8*)(Bl + brow * 72 + kk * 32 + l4 * 8);
        acc[ct] = mfma16(af, bf, acc[ct]);
      }
    }
    __syncthreads();
  }

  // bias + channel-LN per row (rows r = l4*4+i, cols ct*16+l15)
  float bv_[16], scv[16], lbv[16];
  #pragma unroll
  for (int ct = 0; ct < 16; ct++) {
    int c = ct * 16 + l15;
    bv_[ct] = bias[c]; scv[ct] = lsc[c]; lbv[ct] = lbi[c];
  }
  unsigned short* ob = qkv + ((size_t)(tensor * Bn + b) * Nn) * Cn;
  #pragma unroll
  for (int i = 0; i < 4; i++) {
    float s = 0.f, s2 = 0.f;
    #pragma unroll
    for (int ct = 0; ct < 16; ct++) {
      float v = acc[ct][i] + bv_[ct];
      s += v; s2 += v * v;
    }
    s  += __shfl_xor(s, 1);  s  += __shfl_xor(s, 2);
    s  += __shfl_xor(s, 4);  s  += __shfl_xor(s, 8);
    s2 += __shfl_xor(s2, 1); s2 += __shfl_xor(s2, 2);
    s2 += __shfl_xor(s2, 4); s2 += __shfl_xor(s2, 8);
    float mean = s * (1.f / 256.f);
    float var  = s2 * (1.f / 256.f) - mean * mean;
    float inv  = rsqrtf(var + 1e-5f);
    int nn = n0 + wave * 16 + l4 * 4 + i;
    unsigned short* orow = ob + (size_t)nn * Cn;
    #pragma unroll
    for (int ct = 0; ct < 16; ct++) {
      float v = acc[ct][i] + bv_[ct];
      orow[ct * 16 + l15] = f2bf((v - mean) * inv * scv[ct] + lbv[ct]);
    }
  }
}

// ---------------------------------------------------------------------------
// 5) Flash attention partials — R16/R18 configuration exactly (KVB=64, grid
//    dim3(64,2,4), 256 thr, 2 barriers/step, bf16 Opart).
// ---------------------------------------------------------------------------
__global__ __launch_bounds__(256, 2) void flash_kernel(
    const unsigned short* __restrict__ qkv, unsigned short* __restrict__ Opart,
    float* __restrict__ ml) {
  __shared__ unsigned short Ks[KVB][264];
  __shared__ unsigned short Vt[256][72];
  __shared__ unsigned short Pl[4][16][72];
  const int tid = threadIdx.x, lane = tid & 63, wave = tid >> 6;
  const int l15 = lane & 15, l4 = lane >> 4;
  const int qt = blockIdx.x, b = blockIdx.y, sp = blockIdx.z;
  const unsigned short* Q = qkv + (size_t)(0 * Bn + b) * Nn * Cn;
  const unsigned short* K = qkv + (size_t)(1 * Bn + b) * Nn * Cn;
  const unsigned short* V = qkv + (size_t)(2 * Bn + b) * Nn * Cn;
  const int q0 = qt * 64 + wave * 16;

  short8 qf[8];
  {
    const unsigned short* qp = Q + (size_t)(q0 + l15) * Cn + l4 * 8;
    #pragma unroll
    for (int kk = 0; kk < 8; kk++) qf[kk] = *(const short8*)(qp + kk * 32);
  }
  f32x4 acc_o[16];
  #pragma unroll
  for (int i = 0; i < 16; i++) acc_o[i] = (f32x4){0.f, 0.f, 0.f, 0.f};
  float m_r[4], l_r[4];
  #pragma unroll
  for (int i = 0; i < 4; i++) { m_r[i] = -1e30f; l_r[i] = 0.f; }

  const int kvbase = sp * (Nn / SPLIT);
  const float scl = 0.0625f;                  // 1/sqrt(256)

  for (int step = 0; step < NSTEP; step++) {
    int kv0 = kvbase + step * KVB;
    { // stage K: 64 rows, 4 threads/row, contiguous 128B (8 x uint4) each
      int r = tid >> 2, cp = tid & 3;
      const unsigned short* src = K + (size_t)(kv0 + r) * Cn + cp * 64;
      uint4* dst = (uint4*)&Ks[r][cp * 64];
      #pragma unroll
      for (int i = 0; i < 8; i++) dst[i] = ((const uint4*)src)[i];
    }
    { // stage V transposed: 2 k-rows x 32 ch per thread, packed b32 writes
      int rp = (tid & 31) * 2, ch = (tid >> 5) * 32;
      const unsigned short* s0p = V + (size_t)(kv0 + rp) * Cn + ch;
      const unsigned short* s1p = s0p + Cn;
      union { uint4 v[4]; unsigned short u[32]; } r0, r1;
      #pragma unroll
      for (int i = 0; i < 4; i++) {
        r0.v[i] = ((const uint4*)s0p)[i];
        r1.v[i] = ((const uint4*)s1p)[i];
      }
      #pragma unroll
      for (int j = 0; j < 32; j++) {
        unsigned int pack = (unsigned int)r0.u[j] | ((unsigned int)r1.u[j] << 16);
        *(unsigned int*)&Vt[ch + j][rp] = pack;
      }
    }
    __syncthreads();

    // S = Q K^T over four 16-col tiles
    f32x4 s[4];
    #pragma unroll
    for (int t = 0; t < 4; t++) s[t] = (f32x4){0.f, 0.f, 0.f, 0.f};
    #pragma unroll
    for (int kk = 0; kk < 8; kk++) {
      #pragma unroll
      for (int t = 0; t < 4; t++) {
        short8 bt = *(const short8*)&Ks[t * 16 + l15][kk * 32 + l4 * 8];
        s[t] = mfma16(qf[kk], bt, s[t]);
      }
    }

    // online softmax (rows = l4*4+i, 64 cols = 4 subtiles x 16 lanes)
    float p[4][4], al[4];
    #pragma unroll
    for (int i = 0; i < 4; i++) {
      float a0 = s[0][i] * scl, a1 = s[1][i] * scl;
      float a2 = s[2][i] * scl, a3 = s[3][i] * scl;
      float mt = fmaxf(fmaxf(a0, a1), fmaxf(a2, a3));
      mt = fmaxf(mt, __shfl_xor(mt, 1));
      mt = fmaxf(mt, __shfl_xor(mt, 2));
      mt = fmaxf(mt, __shfl_xor(mt, 4));
      mt = fmaxf(mt, __shfl_xor(mt, 8));
      float mn = fmaxf(m_r[i], mt);
      float a = __expf(m_r[i] - mn);
      m_r[i] = mn; al[i] = a;
      p[0][i] = __expf(a0 - mn);
      p[1][i] = __expf(a1 - mn);
      p[2][i] = __expf(a2 - mn);
      p[3][i] = __expf(a3 - mn);
      float r = (p[0][i] + p[1][i]) + (p[2][i] + p[3][i]);
      r += __shfl_xor(r, 1); r += __shfl_xor(r, 2);
      r += __shfl_xor(r, 4); r += __shfl_xor(r, 8);
      l_r[i] = l_r[i] * a + r;
    }
    // P -> LDS (bf16) in A-fragment layout
    #pragma unroll
    for (int i = 0; i < 4; i++) {
      int row = l4 * 4 + i;
      #pragma unroll
      for (int t = 0; t < 4; t++)
        Pl[wave][row][t * 16 + l15] = f2bf(p[t][i]);
    }
    // rescale O
    #pragma unroll
    for (int ct = 0; ct < 16; ct++)
      #pragma unroll
      for (int i = 0; i < 4; i++) acc_o[ct][i] *= al[i];

    // PV over two K=32 slices
    short8 pf0 = *(const short8*)&Pl[wave][l15][l4 * 8];
    short8 pf1 = *(const short8*)&Pl[wave][l15][32 + l4 * 8];
    #pragma unroll
    for (int ct = 0; ct < 16; ct++) {
      short8 vf0 = *(const short8*)&Vt[ct * 16 + l15][l4 * 8];
      short8 vf1 = *(const short8*)&Vt[ct * 16 + l15][32 + l4 * 8];
      acc_o[ct] = mfma16(pf0, vf0, acc_o[ct]);
      acc_o[ct] = mfma16(pf1, vf1, acc_o[ct]);
    }
    __syncthreads();
  }

  // write unnormalized partials (bf16) + (m,l)
  unsigned short* ob = Opart + ((size_t)(sp * Bn + b) * Nn) * Cn;
  #pragma unroll
  for (int ct = 0; ct < 16; ct++) {
    int c = ct * 16 + l15;
    #pragma unroll
    for (int i = 0; i < 4; i++) {
      int nn = q0 + l4 * 4 + i;
      ob[(size_t)nn * Cn + c] = f2bf(acc_o[ct][i]);
    }
  }
  if (l15 == 0) {
    #pragma unroll
    for (int i = 0; i < 4; i++) {
      int nn = q0 + l4 * 4 + i;
      size_t mb = (((size_t)sp * Bn + b) * Nn + nn) * 2;
      ml[mb]     = m_r[i];
      ml[mb + 1] = l_r[i];
    }
  }
}

// ---------------------------------------------------------------------------
// 6) Combine splits + out = gamma*att + xgT (bf16 residual, fused at T-fill),
//    transposed to [b][c][n] via LDS.
// ---------------------------------------------------------------------------
__global__ __launch_bounds__(256) void combine_kernel(
    const unsigned short* __restrict__ Opart, const float* __restrict__ ml,
    const unsigned short* __restrict__ xgT, const float* __restrict__ gamma,
    float* __restrict__ out) {
  __shared__ float T[256][17];
  const int tid = threadIdx.x;
  const int n0 = blockIdx.x * 16;
  const int b = blockIdx.y;
  const float g = gamma[0];
  for (int r = 0; r < 16; r++) {
    int n = n0 + r;
    float msp[SPLIT], lsp[SPLIT];
    float mm = -1e30f;
    #pragma unroll
    for (int s = 0; s < SPLIT; s++) {
      size_t mb = (((size_t)s * Bn + b) * Nn + n) * 2;
      msp[s] = ml[mb]; lsp[s] = ml[mb + 1];
      mm = fmaxf(mm, msp[s]);
    }
    float denom = 0.f, w[SPLIT];
    #pragma unroll
    for (int s = 0; s < SPLIT; s++) { w[s] = __expf(msp[s] - mm); denom += w[s] * lsp[s]; }
    float inv = 1.f / denom;
    float acc = 0.f;
    #pragma unroll
    for (int s = 0; s < SPLIT; s++)
      acc += w[s] * bf2f(Opart[(((size_t)s * Bn + b) * Nn + n) * Cn + tid]);
    float res = bf2f(xgT[((size_t)(b * Nn + n)) * Cn + tid]);
    T[tid][r] = g * acc * inv + res;
  }
  __syncthreads();
  const int c = tid;
  float4* op = (float4*)(out + ((size_t)(b * Cn + c)) * Nn + n0);
  #pragma unroll
  for (int r4 = 0; r4 < 4; r4++) {
    float4 vv;
    vv.x = T[c][r4 * 4 + 0];
    vv.y = T[c][r4 * 4 + 1];
    vv.z = T[c][r4 * 4 + 2];
    vv.w = T[c][r4 * 4 + 3];
    op[r4] = vv;
  }
}

// ---------------------------------------------------------------------------
extern "C" void kernel_launch(void* const* d_in, const int* in_sizes, int n_in,
                              void* d_out, int out_size, void* d_ws, size_t ws_size,
                              hipStream_t stream) {
  const float* x   = (const float*)d_in[0];
  const float* w1  = (const float*)d_in[1];
  const float* b1  = (const float*)d_in[2];
  const float* w2i = (const float*)d_in[3];
  const float* b2  = (const float*)d_in[4];
  const float* w3  = (const float*)d_in[5];
  const float* b3  = (const float*)d_in[6];
  const float* w4  = (const float*)d_in[7];
  const float* b4  = (const float*)d_in[8];
  const float* wq  = (const float*)d_in[9];
  const float* bq  = (const float*)d_in[10];
  const float* wk  = (const float*)d_in[11];
  const float* bk  = (const float*)d_in[12];
  const float* wv  = (const float*)d_in[13];
  const float* bv  = (const float*)d_in[14];
  const float* qs  = (const float*)d_in[15];
  const float* qb  = (const float*)d_in[16];
  const float* ks  = (const float*)d_in[17];
  const float* kb  = (const float*)d_in[18];
  const float* vs  = (const float*)d_in[19];
  const float* vb  = (const float*)d_in[20];
  const float* gamma = (const float*)d_in[21];
  float* out = (float*)d_out;

  char* ws = (char*)d_ws;
  unsigned short* xgT   = (unsigned short*)(ws + 0);         //  4.19 MB
  unsigned short* w2b   = (unsigned short*)(ws + 4194304);   //  1.18 MB
  unsigned short* qkv   = (unsigned short*)(ws + 5373952);   // 12.58 MB
  unsigned short* Opart = (unsigned short*)(ws + 17956864);  // 16.78 MB (bf16, SPLIT=4)
  float* ml             = (float*)(ws + 34734080);           //  0.26 MB (end 35.0MB)

  prep_w_kernel<<<dim3(2304), dim3(256), 0, stream>>>(wq, wk, wv, w2b);
  gated_kernel<<<dim3(64, 4, 2), dim3(256), 0, stream>>>(
      x, w1, b1, w2i, b2, w3, b3, w4, b4, xgT);
  qkvconv_ln_kernel<<<dim3(128, 2, 3), dim3(128), 0, stream>>>(
      xgT, w2b, bq, bk, bv, qs, qb, ks, kb, vs, vb, qkv);
  flash_kernel<<<dim3(64, 2, SPLIT), dim3(256), 0, stream>>>(qkv, Opart, ml);
  combine_kernel<<<dim3(256, 2), dim3(256), 0, stream>>>(Opart, ml, xgT, gamma, out);
}

// Round 20
// 149.601 us; speedup vs baseline: 1.2096x; 1.0299x over previous
//
#include <hip/hip_runtime.h>

// Problem constants
#define Bn 2
#define Cn 256
#define Nn 4096
#define SPLIT 4
#define KVB 64
#define NSTEP ((Nn / SPLIT) / KVB)

typedef __attribute__((ext_vector_type(8))) short short8;
typedef __attribute__((ext_vector_type(4))) float f32x4;

__device__ __forceinline__ unsigned short f2bf(float f) {
  union { float f; unsigned int u; } v; v.f = f;
  unsigned int r = (v.u + 0x7FFFu + ((v.u >> 16) & 1u)) >> 16;
  return (unsigned short)r;
}
__device__ __forceinline__ float bf2f(unsigned short u) {
  union { unsigned int i; float f; } v; v.i = ((unsigned int)u) << 16; return v.f;
}

__device__ __forceinline__ f32x4 mfma16(short8 a, short8 b, f32x4 c) {
  return __builtin_amdgcn_mfma_f32_16x16x32_bf16(a, b, c, 0, 0, 0);
}

// ---------------------------------------------------------------------------
// 1+2) Fat kernel: bid<512 -> gated channel-split 1x1x1 convs + SiLU
//      (writes xgT bf16 [b][n][c]);  bid>=512 -> weight transpose
//      [co][ci][t] -> bf16 w2[tensor][t][co][ci].  Paths are independent.
// ---------------------------------------------------------------------------
__global__ __launch_bounds__(256) void gated_prepw_kernel(
    const float* __restrict__ x,
    const float* __restrict__ w1, const float* __restrict__ b1,
    const float* __restrict__ w2, const float* __restrict__ b2,
    const float* __restrict__ w3, const float* __restrict__ b3,
    const float* __restrict__ w4, const float* __restrict__ b4,
    const float* __restrict__ wq, const float* __restrict__ wk,
    const float* __restrict__ wv,
    unsigned short* __restrict__ xgT, unsigned short* __restrict__ w2b) {
  const int bid = blockIdx.x;
  const int tid = threadIdx.x;
  if (bid >= 512) {  // ---- prep_w path (2304 blocks) ----
    int idx = (bid - 512) * 256 + tid;          // 3*3*256*256 = 589824
    int tensor = idx / 196608;
    int rem = idx % 196608;
    int t  = rem >> 16;
    int co = (rem >> 8) & 255;
    int ci = rem & 255;
    const float* w = (tensor == 0) ? wq : (tensor == 1) ? wk : wv;
    w2b[idx] = f2bf(w[(co * 256 + ci) * 3 + t]);
    return;
  }
  // ---- gated path (512 blocks): n0 = (bid&63)*64, q = (bid>>6)&3, b = bid>>8
  __shared__ float Wl[64][65];
  __shared__ float Xl[64][65];
  __shared__ unsigned short Yl[64][72];
  const int n0 = (bid & 63) * 64;
  const int q  = (bid >> 6) & 3;
  const int b  = bid >> 8;
  const float* wsel = (q == 0) ? w1 : (q == 1) ? w2 : (q == 2) ? w3 : w4;
  const float* bsel = (q == 0) ? b1 : (q == 1) ? b2 : (q == 2) ? b3 : b4;

  #pragma unroll
  for (int it = 0; it < 4; it++) {
    int i = (tid + it * 256) * 4;
    float4 v = *(const float4*)(wsel + i);
    int co = i >> 6, ci = i & 63;
    Wl[co][ci] = v.x; Wl[co][ci + 1] = v.y; Wl[co][ci + 2] = v.z; Wl[co][ci + 3] = v.w;
  }
  {
    int ci = tid >> 2, part = tid & 3;
    const float* src = x + ((size_t)(b * Cn + q * 64 + ci)) * Nn + n0 + part * 16;
    #pragma unroll
    for (int j = 0; j < 4; j++) {
      float4 v = ((const float4*)src)[j];
      float* dst = &Xl[ci][part * 16 + j * 4];
      dst[0] = v.x; dst[1] = v.y; dst[2] = v.z; dst[3] = v.w;
    }
  }
  __syncthreads();
  const int co = tid >> 2, npart = tid & 3;
  float acc[16];
  {
    float bias = bsel[co];
    #pragma unroll
    for (int j = 0; j < 16; j++) acc[j] = bias;
  }
  for (int ci = 0; ci < 64; ci++) {
    float wv_ = Wl[co][ci];
    const float* xr = &Xl[ci][npart * 16];
    #pragma unroll
    for (int j = 0; j < 16; j++) acc[j] += wv_ * xr[j];
  }
  #pragma unroll
  for (int j = 0; j < 16; j++) {
    float v = acc[j];
    float s = v / (1.f + __expf(-v));   // SiLU
    Yl[npart * 16 + j][co] = f2bf(s);
  }
  __syncthreads();
  { // transpose-out: 4 threads per row, 16 channels each -> full 64x64 tile
    int r = tid >> 2, cp = tid & 3;
    union { unsigned short u[16]; uint4 v[2]; } pk;
    #pragma unroll
    for (int j = 0; j < 16; j++) pk.u[j] = Yl[r][cp * 16 + j];
    uint4* dst = (uint4*)(xgT + ((size_t)(b * Nn + n0 + r)) * Cn + q * 64 + cp * 16);
    dst[0] = pk.v[0];
    dst[1] = pk.v[1];
  }
}

// ---------------------------------------------------------------------------
// 3) QKV directional convs + fused channel LayerNorm.  M-tile = 32 rows,
//    128 thr / 2 waves, grid (128,2,3) = 768 blocks = 3 blocks/CU.
// ---------------------------------------------------------------------------
__global__ __launch_bounds__(128) void qkvconv_ln_kernel(
    const unsigned short* __restrict__ xgT, const unsigned short* __restrict__ w2,
    const float* __restrict__ bq, const float* __restrict__ bk,
    const float* __restrict__ bv,
    const float* __restrict__ qs, const float* __restrict__ qb,
    const float* __restrict__ ks, const float* __restrict__ kb,
    const float* __restrict__ vs, const float* __restrict__ vb,
    unsigned short* __restrict__ qkv) {
  __shared__ unsigned short Al[32 * 72];
  __shared__ unsigned short Bl[256 * 72];
  const int tid = threadIdx.x;
  const int lane = tid & 63, wave = tid >> 6;
  const int l15 = lane & 15, l4 = lane >> 4;
  const int n0  = blockIdx.x * 32;
  const int b = blockIdx.y;
  const int tensor = blockIdx.z;
  const int cstride = (tensor == 0) ? 16 : (tensor == 1) ? 1 : 256;   // H, W, D
  const float* bias = (tensor == 0) ? bq : (tensor == 1) ? bk : bv;
  const float* lsc = (tensor == 0) ? qs : (tensor == 1) ? ks : vs;
  const float* lbi = (tensor == 0) ? qb : (tensor == 1) ? kb : vb;
  const unsigned short* wbase = w2 + (size_t)tensor * 196608;
  const unsigned short* xbase = xgT + (size_t)b * Nn * Cn;

  f32x4 acc[16];
  #pragma unroll
  for (int i = 0; i < 16; i++) acc[i] = (f32x4){0.f, 0.f, 0.f, 0.f};

  const int arow = tid >> 2, akp = tid & 3;     // A staging: row (0..31), 16-ch chunk
  const int n = n0 + arow;
  const int coordv = (n / cstride) & 15;        // coordinate along conv axis

  for (int kc = 0; kc < 12; kc++) {             // 12 chunks of K=64
    int t = kc >> 2;
    int cib = (kc & 3) * 64;
    int shift = t - 1;
    int c2 = coordv + shift;
    { // A: 32 rows x 64ch, 16 ch (2 x uint4) per thread
      const unsigned short* asrc =
          xbase + ((size_t)(n + shift * cstride)) * Cn + cib + akp * 16;
      uint4 av0 = (c2 >= 0 && c2 < 16) ? ((const uint4*)asrc)[0] : (uint4){0, 0, 0, 0};
      uint4 av1 = (c2 >= 0 && c2 < 16) ? ((const uint4*)asrc)[1] : (uint4){0, 0, 0, 0};
      uint4* ad = (uint4*)(Al + arow * 72 + akp * 16);
      ad[0] = av0; ad[1] = av1;
    }
    { // B: 256 rows x 64ch, rows tid>>2 + 32i (i=0..7), 16 ch per thread per row
      #pragma unroll
      for (int i = 0; i < 8; i++) {
        int row = (tid >> 2) + 32 * i;
        const unsigned short* bsrc =
            wbase + ((size_t)(t * 256 + row)) * 256 + cib + akp * 16;
        uint4* bd = (uint4*)(Bl + row * 72 + akp * 16);
        bd[0] = ((const uint4*)bsrc)[0];
        bd[1] = ((const uint4*)bsrc)[1];
      }
    }
    __syncthreads();
    int arowf = wave * 16 + l15;
    #pragma unroll
    for (int kk = 0; kk < 2; kk++) {
      short8 af = *(const short8*)(Al + arowf * 72 + kk * 32 + l4 * 8);
      #pragma unroll
      for (int ct = 0; ct < 16; ct++) {
        int brow = ct * 16 + l15;
        short8 bf = *(const short8*)(Bl + brow * 72 + kk * 32 + l4 * 8);
        acc[ct] = mfma16(af, bf, acc[ct]);
      }
    }
    __syncthreads();
  }

  // bias + channel-LN per row (rows r = l4*4+i, cols ct*16+l15)
  float bv_[16], scv[16], lbv[16];
  #pragma unroll
  for (int ct = 0; ct < 16; ct++) {
    int c = ct * 16 + l15;
    bv_[ct] = bias[c]; scv[ct] = lsc[c]; lbv[ct] = lbi[c];
  }
  unsigned short* ob = qkv + ((size_t)(tensor * Bn + b) * Nn) * Cn;
  #pragma unroll
  for (int i = 0; i < 4; i++) {
    float s = 0.f, s2 = 0.f;
    #pragma unroll
    for (int ct = 0; ct < 16; ct++) {
      float v = acc[ct][i] + bv_[ct];
      s += v; s2 += v * v;
    }
    s  += __shfl_xor(s, 1);  s  += __shfl_xor(s, 2);
    s  += __shfl_xor(s, 4);  s  += __shfl_xor(s, 8);
    s2 += __shfl_xor(s2, 1); s2 += __shfl_xor(s2, 2);
    s2 += __shfl_xor(s2, 4); s2 += __shfl_xor(s2, 8);
    float mean = s * (1.f / 256.f);
    float var  = s2 * (1.f / 256.f) - mean * mean;
    float inv  = rsqrtf(var + 1e-5f);
    int nn = n0 + wave * 16 + l4 * 4 + i;
    unsigned short* orow = ob + (size_t)nn * Cn;
    #pragma unroll
    for (int ct = 0; ct < 16; ct++) {
      float v = acc[ct][i] + bv_[ct];
      orow[ct * 16 + l15] = f2bf((v - mean) * inv * scv[ct] + lbv[ct]);
    }
  }
}

// ---------------------------------------------------------------------------
// 5) Flash attention partials — R16/R18 configuration exactly (KVB=64, grid
//    dim3(64,2,4), 256 thr, 2 barriers/step, bf16 Opart).
// ---------------------------------------------------------------------------
__global__ __launch_bounds__(256, 2) void flash_kernel(
    const unsigned short* __restrict__ qkv, unsigned short* __restrict__ Opart,
    float* __restrict__ ml) {
  __shared__ unsigned short Ks[KVB][264];
  __shared__ unsigned short Vt[256][72];
  __shared__ unsigned short Pl[4][16][72];
  const int tid = threadIdx.x, lane = tid & 63, wave = tid >> 6;
  const int l15 = lane & 15, l4 = lane >> 4;
  const int qt = blockIdx.x, b = blockIdx.y, sp = blockIdx.z;
  const unsigned short* Q = qkv + (size_t)(0 * Bn + b) * Nn * Cn;
  const unsigned short* K = qkv + (size_t)(1 * Bn + b) * Nn * Cn;
  const unsigned short* V = qkv + (size_t)(2 * Bn + b) * Nn * Cn;
  const int q0 = qt * 64 + wave * 16;

  short8 qf[8];
  {
    const unsigned short* qp = Q + (size_t)(q0 + l15) * Cn + l4 * 8;
    #pragma unroll
    for (int kk = 0; kk < 8; kk++) qf[kk] = *(const short8*)(qp + kk * 32);
  }
  f32x4 acc_o[16];
  #pragma unroll
  for (int i = 0; i < 16; i++) acc_o[i] = (f32x4){0.f, 0.f, 0.f, 0.f};
  float m_r[4], l_r[4];
  #pragma unroll
  for (int i = 0; i < 4; i++) { m_r[i] = -1e30f; l_r[i] = 0.f; }

  const int kvbase = sp * (Nn / SPLIT);
  const float scl = 0.0625f;                  // 1/sqrt(256)

  for (int step = 0; step < NSTEP; step++) {
    int kv0 = kvbase + step * KVB;
    { // stage K: 64 rows, 4 threads/row, contiguous 128B (8 x uint4) each
      int r = tid >> 2, cp = tid & 3;
      const unsigned short* src = K + (size_t)(kv0 + r) * Cn + cp * 64;
      uint4* dst = (uint4*)&Ks[r][cp * 64];
      #pragma unroll
      for (int i = 0; i < 8; i++) dst[i] = ((const uint4*)src)[i];
    }
    { // stage V transposed: 2 k-rows x 32 ch per thread, packed b32 writes
      int rp = (tid & 31) * 2, ch = (tid >> 5) * 32;
      const unsigned short* s0p = V + (size_t)(kv0 + rp) * Cn + ch;
      const unsigned short* s1p = s0p + Cn;
      union { uint4 v[4]; unsigned short u[32]; } r0, r1;
      #pragma unroll
      for (int i = 0; i < 4; i++) {
        r0.v[i] = ((const uint4*)s0p)[i];
        r1.v[i] = ((const uint4*)s1p)[i];
      }
      #pragma unroll
      for (int j = 0; j < 32; j++) {
        unsigned int pack = (unsigned int)r0.u[j] | ((unsigned int)r1.u[j] << 16);
        *(unsigned int*)&Vt[ch + j][rp] = pack;
      }
    }
    __syncthreads();

    // S = Q K^T over four 16-col tiles
    f32x4 s[4];
    #pragma unroll
    for (int t = 0; t < 4; t++) s[t] = (f32x4){0.f, 0.f, 0.f, 0.f};
    #pragma unroll
    for (int kk = 0; kk < 8; kk++) {
      #pragma unroll
      for (int t = 0; t < 4; t++) {
        short8 bt = *(const short8*)&Ks[t * 16 + l15][kk * 32 + l4 * 8];
        s[t] = mfma16(qf[kk], bt, s[t]);
      }
    }

    // online softmax (rows = l4*4+i, 64 cols = 4 subtiles x 16 lanes)
    float p[4][4], al[4];
    #pragma unroll
    for (int i = 0; i < 4; i++) {
      float a0 = s[0][i] * scl, a1 = s[1][i] * scl;
      float a2 = s[2][i] * scl, a3 = s[3][i] * scl;
      float mt = fmaxf(fmaxf(a0, a1), fmaxf(a2, a3));
      mt = fmaxf(mt, __shfl_xor(mt, 1));
      mt = fmaxf(mt, __shfl_xor(mt, 2));
      mt = fmaxf(mt, __shfl_xor(mt, 4));
      mt = fmaxf(mt, __shfl_xor(mt, 8));
      float mn = fmaxf(m_r[i], mt);
      float a = __expf(m_r[i] - mn);
      m_r[i] = mn; al[i] = a;
      p[0][i] = __expf(a0 - mn);
      p[1][i] = __expf(a1 - mn);
      p[2][i] = __expf(a2 - mn);
      p[3][i] = __expf(a3 - mn);
      float r = (p[0][i] + p[1][i]) + (p[2][i] + p[3][i]);
      r += __shfl_xor(r, 1); r += __shfl_xor(r, 2);
      r += __shfl_xor(r, 4); r += __shfl_xor(r, 8);
      l_r[i] = l_r[i] * a + r;
    }
    // P -> LDS (bf16) in A-fragment layout
    #pragma unroll
    for (int i = 0; i < 4; i++) {
      int row = l4 * 4 + i;
      #pragma unroll
      for (int t = 0; t < 4; t++)
        Pl[wave][row][t * 16 + l15] = f2bf(p[t][i]);
    }
    // rescale O
    #pragma unroll
    for (int ct = 0; ct < 16; ct++)
      #pragma unroll
      for (int i = 0; i < 4; i++) acc_o[ct][i] *= al[i];

    // PV over two K=32 slices
    short8 pf0 = *(const short8*)&Pl[wave][l15][l4 * 8];
    short8 pf1 = *(const short8*)&Pl[wave][l15][32 + l4 * 8];
    #pragma unroll
    for (int ct = 0; ct < 16; ct++) {
      short8 vf0 = *(const short8*)&Vt[ct * 16 + l15][l4 * 8];
      short8 vf1 = *(const short8*)&Vt[ct * 16 + l15][32 + l4 * 8];
      acc_o[ct] = mfma16(pf0, vf0, acc_o[ct]);
      acc_o[ct] = mfma16(pf1, vf1, acc_o[ct]);
    }
    __syncthreads();
  }

  // write unnormalized partials (bf16) + (m,l)
  unsigned short* ob = Opart + ((size_t)(sp * Bn + b) * Nn) * Cn;
  #pragma unroll
  for (int ct = 0; ct < 16; ct++) {
    int c = ct * 16 + l15;
    #pragma unroll
    for (int i = 0; i < 4; i++) {
      int nn = q0 + l4 * 4 + i;
      ob[(size_t)nn * Cn + c] = f2bf(acc_o[ct][i]);
    }
  }
  if (l15 == 0) {
    #pragma unroll
    for (int i = 0; i < 4; i++) {
      int nn = q0 + l4 * 4 + i;
      size_t mb = (((size_t)sp * Bn + b) * Nn + nn) * 2;
      ml[mb]     = m_r[i];
      ml[mb + 1] = l_r[i];
    }
  }
}

// ---------------------------------------------------------------------------
// 6) Combine splits + out = gamma*att + xgT (bf16 residual, fused at T-fill),
//    transposed to [b][c][n] via LDS.
// ---------------------------------------------------------------------------
__global__ __launch_bounds__(256) void combine_kernel(
    const unsigned short* __restrict__ Opart, const float* __restrict__ ml,
    const unsigned short* __restrict__ xgT, const float* __restrict__ gamma,
    float* __restrict__ out) {
  __shared__ float T[256][17];
  const int tid = threadIdx.x;
  const int n0 = blockIdx.x * 16;
  const int b = blockIdx.y;
  const float g = gamma[0];
  for (int r = 0; r < 16; r++) {
    int n = n0 + r;
    float msp[SPLIT], lsp[SPLIT];
    float mm = -1e30f;
    #pragma unroll
    for (int s = 0; s < SPLIT; s++) {
      size_t mb = (((size_t)s * Bn + b) * Nn + n) * 2;
      msp[s] = ml[mb]; lsp[s] = ml[mb + 1];
      mm = fmaxf(mm, msp[s]);
    }
    float denom = 0.f, w[SPLIT];
    #pragma unroll
    for (int s = 0; s < SPLIT; s++) { w[s] = __expf(msp[s] - mm); denom += w[s] * lsp[s]; }
    float inv = 1.f / denom;
    float acc = 0.f;
    #pragma unroll
    for (int s = 0; s < SPLIT; s++)
      acc += w[s] * bf2f(Opart[(((size_t)s * Bn + b) * Nn + n) * Cn + tid]);
    float res = bf2f(xgT[((size_t)(b * Nn + n)) * Cn + tid]);
    T[tid][r] = g * acc * inv + res;
  }
  __syncthreads();
  const int c = tid;
  float4* op = (float4*)(out + ((size_t)(b * Cn + c)) * Nn + n0);
  #pragma unroll
  for (int r4 = 0; r4 < 4; r4++) {
    float4 vv;
    vv.x = T[c][r4 * 4 + 0];
    vv.y = T[c][r4 * 4 + 1];
    vv.z = T[c][r4 * 4 + 2];
    vv.w = T[c][r4 * 4 + 3];
    op[r4] = vv;
  }
}

// ---------------------------------------------------------------------------
extern "C" void kernel_launch(void* const* d_in, const int* in_sizes, int n_in,
                              void* d_out, int out_size, void* d_ws, size_t ws_size,
                              hipStream_t stream) {
  const float* x   = (const float*)d_in[0];
  const float* w1  = (const float*)d_in[1];
  const float* b1  = (const float*)d_in[2];
  const float* w2i = (const float*)d_in[3];
  const float* b2  = (const float*)d_in[4];
  const float* w3  = (const float*)d_in[5];
  const float* b3  = (const float*)d_in[6];
  const float* w4  = (const float*)d_in[7];
  const float* b4  = (const float*)d_in[8];
  const float* wq  = (const float*)d_in[9];
  const float* bq  = (const float*)d_in[10];
  const float* wk  = (const float*)d_in[11];
  const float* bk  = (const float*)d_in[12];
  const float* wv  = (const float*)d_in[13];
  const float* bv  = (const float*)d_in[14];
  const float* qs  = (const float*)d_in[15];
  const float* qb  = (const float*)d_in[16];
  const float* ks  = (const float*)d_in[17];
  const float* kb  = (const float*)d_in[18];
  const float* vs  = (const float*)d_in[19];
  const float* vb  = (const float*)d_in[20];
  const float* gamma = (const float*)d_in[21];
  float* out = (float*)d_out;

  char* ws = (char*)d_ws;
  unsigned short* xgT   = (unsigned short*)(ws + 0);         //  4.19 MB
  unsigned short* w2b   = (unsigned short*)(ws + 4194304);   //  1.18 MB
  unsigned short* qkv   = (unsigned short*)(ws + 5373952);   // 12.58 MB
  unsigned short* Opart = (unsigned short*)(ws + 17956864);  // 16.78 MB (bf16, SPLIT=4)
  float* ml             = (float*)(ws + 34734080);           //  0.26 MB (end 35.0MB)

  gated_prepw_kernel<<<dim3(2816), dim3(256), 0, stream>>>(
      x, w1, b1, w2i, b2, w3, b3, w4, b4, wq, wk, wv, xgT, w2b);
  qkvconv_ln_kernel<<<dim3(128, 2, 3), dim3(128), 0, stream>>>(
      xgT, w2b, bq, bk, bv, qs, qb, ks, kb, vs, vb, qkv);
  flash_kernel<<<dim3(64, 2, SPLIT), dim3(256), 0, stream>>>(qkv, Opart, ml);
  combine_kernel<<<dim3(256, 2), dim3(256), 0, stream>>>(Opart, ml, xgT, gamma, out);
}

// Round 21
// 147.753 us; speedup vs baseline: 1.2247x; 1.0125x over previous
//
#include <hip/hip_runtime.h>

// Problem constants
#define Bn 2
#define Cn 256
#define Nn 4096
#define SPLIT 4
#define KVB 64
#define NSTEP ((Nn / SPLIT) / KVB)

typedef __attribute__((ext_vector_type(8))) short short8;
typedef __attribute__((ext_vector_type(4))) float f32x4;

__device__ __forceinline__ unsigned short f2bf(float f) {
  union { float f; unsigned int u; } v; v.f = f;
  unsigned int r = (v.u + 0x7FFFu + ((v.u >> 16) & 1u)) >> 16;
  return (unsigned short)r;
}
__device__ __forceinline__ float bf2f(unsigned short u) {
  union { unsigned int i; float f; } v; v.i = ((unsigned int)u) << 16; return v.f;
}

__device__ __forceinline__ f32x4 mfma16(short8 a, short8 b, f32x4 c) {
  return __builtin_amdgcn_mfma_f32_16x16x32_bf16(a, b, c, 0, 0, 0);
}

// ---------------------------------------------------------------------------
// 1+2) Fat kernel: bid<512 -> gated channel-split 1x1x1 convs + SiLU
//      (writes xgT bf16 [b][n][c]);  bid>=512 -> weight transpose
//      [co][ci][t] -> bf16 w2[tensor][t][co][ci].  Paths are independent.
// ---------------------------------------------------------------------------
__global__ __launch_bounds__(256) void gated_prepw_kernel(
    const float* __restrict__ x,
    const float* __restrict__ w1, const float* __restrict__ b1,
    const float* __restrict__ w2, const float* __restrict__ b2,
    const float* __restrict__ w3, const float* __restrict__ b3,
    const float* __restrict__ w4, const float* __restrict__ b4,
    const float* __restrict__ wq, const float* __restrict__ wk,
    const float* __restrict__ wv,
    unsigned short* __restrict__ xgT, unsigned short* __restrict__ w2b) {
  const int bid = blockIdx.x;
  const int tid = threadIdx.x;
  if (bid >= 512) {  // ---- prep_w path (2304 blocks) ----
    int idx = (bid - 512) * 256 + tid;          // 3*3*256*256 = 589824
    int tensor = idx / 196608;
    int rem = idx % 196608;
    int t  = rem >> 16;
    int co = (rem >> 8) & 255;
    int ci = rem & 255;
    const float* w = (tensor == 0) ? wq : (tensor == 1) ? wk : wv;
    w2b[idx] = f2bf(w[(co * 256 + ci) * 3 + t]);
    return;
  }
  // ---- gated path (512 blocks): n0 = (bid&63)*64, q = (bid>>6)&3, b = bid>>8
  __shared__ float Wl[64][65];
  __shared__ float Xl[64][65];
  __shared__ unsigned short Yl[64][72];
  const int n0 = (bid & 63) * 64;
  const int q  = (bid >> 6) & 3;
  const int b  = bid >> 8;
  const float* wsel = (q == 0) ? w1 : (q == 1) ? w2 : (q == 2) ? w3 : w4;
  const float* bsel = (q == 0) ? b1 : (q == 1) ? b2 : (q == 2) ? b3 : b4;

  #pragma unroll
  for (int it = 0; it < 4; it++) {
    int i = (tid + it * 256) * 4;
    float4 v = *(const float4*)(wsel + i);
    int co = i >> 6, ci = i & 63;
    Wl[co][ci] = v.x; Wl[co][ci + 1] = v.y; Wl[co][ci + 2] = v.z; Wl[co][ci + 3] = v.w;
  }
  {
    int ci = tid >> 2, part = tid & 3;
    const float* src = x + ((size_t)(b * Cn + q * 64 + ci)) * Nn + n0 + part * 16;
    #pragma unroll
    for (int j = 0; j < 4; j++) {
      float4 v = ((const float4*)src)[j];
      float* dst = &Xl[ci][part * 16 + j * 4];
      dst[0] = v.x; dst[1] = v.y; dst[2] = v.z; dst[3] = v.w;
    }
  }
  __syncthreads();
  const int co = tid >> 2, npart = tid & 3;
  float acc[16];
  {
    float bias = bsel[co];
    #pragma unroll
    for (int j = 0; j < 16; j++) acc[j] = bias;
  }
  for (int ci = 0; ci < 64; ci++) {
    float wv_ = Wl[co][ci];
    const float* xr = &Xl[ci][npart * 16];
    #pragma unroll
    for (int j = 0; j < 16; j++) acc[j] += wv_ * xr[j];
  }
  #pragma unroll
  for (int j = 0; j < 16; j++) {
    float v = acc[j];
    float s = v / (1.f + __expf(-v));   // SiLU
    Yl[npart * 16 + j][co] = f2bf(s);
  }
  __syncthreads();
  { // transpose-out: 4 threads per row, 16 channels each -> full 64x64 tile
    int r = tid >> 2, cp = tid & 3;
    union { unsigned short u[16]; uint4 v[2]; } pk;
    #pragma unroll
    for (int j = 0; j < 16; j++) pk.u[j] = Yl[r][cp * 16 + j];
    uint4* dst = (uint4*)(xgT + ((size_t)(b * Nn + n0 + r)) * Cn + q * 64 + cp * 16);
    dst[0] = pk.v[0];
    dst[1] = pk.v[1];
  }
}

// ---------------------------------------------------------------------------
// 3) QKV directional convs + fused channel LayerNorm.  M-tile = 32 rows,
//    128 thr / 2 waves, grid (128,2,3) = 768 blocks = 3 blocks/CU.
// ---------------------------------------------------------------------------
__global__ __launch_bounds__(128) void qkvconv_ln_kernel(
    const unsigned short* __restrict__ xgT, const unsigned short* __restrict__ w2,
    const float* __restrict__ bq, const float* __restrict__ bk,
    const float* __restrict__ bv,
    const float* __restrict__ qs, const float* __restrict__ qb,
    const float* __restrict__ ks, const float* __restrict__ kb,
    const float* __restrict__ vs, const float* __restrict__ vb,
    unsigned short* __restrict__ qkv) {
  __shared__ unsigned short Al[32 * 72];
  __shared__ unsigned short Bl[256 * 72];
  const int tid = threadIdx.x;
  const int lane = tid & 63, wave = tid >> 6;
  const int l15 = lane & 15, l4 = lane >> 4;
  const int n0  = blockIdx.x * 32;
  const int b = blockIdx.y;
  const int tensor = blockIdx.z;
  const int cstride = (tensor == 0) ? 16 : (tensor == 1) ? 1 : 256;   // H, W, D
  const float* bias = (tensor == 0) ? bq : (tensor == 1) ? bk : bv;
  const float* lsc = (tensor == 0) ? qs : (tensor == 1) ? ks : vs;
  const float* lbi = (tensor == 0) ? qb : (tensor == 1) ? kb : vb;
  const unsigned short* wbase = w2 + (size_t)tensor * 196608;
  const unsigned short* xbase = xgT + (size_t)b * Nn * Cn;

  f32x4 acc[16];
  #pragma unroll
  for (int i = 0; i < 16; i++) acc[i] = (f32x4){0.f, 0.f, 0.f, 0.f};

  const int arow = tid >> 2, akp = tid & 3;     // A staging: row (0..31), 16-ch chunk
  const int n = n0 + arow;
  const int coordv = (n / cstride) & 15;        // coordinate along conv axis

  for (int kc = 0; kc < 12; kc++) {             // 12 chunks of K=64
    int t = kc >> 2;
    int cib = (kc & 3) * 64;
    int shift = t - 1;
    int c2 = coordv + shift;
    { // A: 32 rows x 64ch, 16 ch (2 x uint4) per thread
      const unsigned short* asrc =
          xbase + ((size_t)(n + shift * cstride)) * Cn + cib + akp * 16;
      uint4 av0 = (c2 >= 0 && c2 < 16) ? ((const uint4*)asrc)[0] : (uint4){0, 0, 0, 0};
      uint4 av1 = (c2 >= 0 && c2 < 16) ? ((const uint4*)asrc)[1] : (uint4){0, 0, 0, 0};
      uint4* ad = (uint4*)(Al + arow * 72 + akp * 16);
      ad[0] = av0; ad[1] = av1;
    }
    { // B: 256 rows x 64ch, rows tid>>2 + 32i (i=0..7), 16 ch per thread per row
      #pragma unroll
      for (int i = 0; i < 8; i++) {
        int row = (tid >> 2) + 32 * i;
        const unsigned short* bsrc =
            wbase + ((size_t)(t * 256 + row)) * 256 + cib + akp * 16;
        uint4* bd = (uint4*)(Bl + row * 72 + akp * 16);
        bd[0] = ((const uint4*)bsrc)[0];
        bd[1] = ((const uint4*)bsrc)[1];
      }
    }
    __syncthreads();
    int arowf = wave * 16 + l15;
    #pragma unroll
    for (int kk = 0; kk < 2; kk++) {
      short8 af = *(const short8*)(Al + arowf * 72 + kk * 32 + l4 * 8);
      #pragma unroll
      for (int ct = 0; ct < 16; ct++) {
        int brow = ct * 16 + l15;
        short8 bf = *(const short8*)(Bl + brow * 72 + kk * 32 + l4 * 8);
        acc[ct] = mfma16(af, bf, acc[ct]);
      }
    }
    __syncthreads();
  }

  // bias + channel-LN per row (rows r = l4*4+i, cols ct*16+l15)
  float bv_[16], scv[16], lbv[16];
  #pragma unroll
  for (int ct = 0; ct < 16; ct++) {
    int c = ct * 16 + l15;
    bv_[ct] = bias[c]; scv[ct] = lsc[c]; lbv[ct] = lbi[c];
  }
  unsigned short* ob = qkv + ((size_t)(tensor * Bn + b) * Nn) * Cn;
  #pragma unroll
  for (int i = 0; i < 4; i++) {
    float s = 0.f, s2 = 0.f;
    #pragma unroll
    for (int ct = 0; ct < 16; ct++) {
      float v = acc[ct][i] + bv_[ct];
      s += v; s2 += v * v;
    }
    s  += __shfl_xor(s, 1);  s  += __shfl_xor(s, 2);
    s  += __shfl_xor(s, 4);  s  += __shfl_xor(s, 8);
    s2 += __shfl_xor(s2, 1); s2 += __shfl_xor(s2, 2);
    s2 += __shfl_xor(s2, 4); s2 += __shfl_xor(s2, 8);
    float mean = s * (1.f / 256.f);
    float var  = s2 * (1.f / 256.f) - mean * mean;
    float inv  = rsqrtf(var + 1e-5f);
    int nn = n0 + wave * 16 + l4 * 4 + i;
    unsigned short* orow = ob + (size_t)nn * Cn;
    #pragma unroll
    for (int ct = 0; ct < 16; ct++) {
      float v = acc[ct][i] + bv_[ct];
      orow[ct * 16 + l15] = f2bf((v - mean) * inv * scv[ct] + lbv[ct]);
    }
  }
}

// ---------------------------------------------------------------------------
// 5) Flash attention partials — R16/R18 configuration exactly (KVB=64, grid
//    dim3(64,2,4), 256 thr, 2 barriers/step, bf16 Opart).
// ---------------------------------------------------------------------------
__global__ __launch_bounds__(256, 2) void flash_kernel(
    const unsigned short* __restrict__ qkv, unsigned short* __restrict__ Opart,
    float* __restrict__ ml) {
  __shared__ unsigned short Ks[KVB][264];
  __shared__ unsigned short Vt[256][72];
  __shared__ unsigned short Pl[4][16][72];
  const int tid = threadIdx.x, lane = tid & 63, wave = tid >> 6;
  const int l15 = lane & 15, l4 = lane >> 4;
  const int qt = blockIdx.x, b = blockIdx.y, sp = blockIdx.z;
  const unsigned short* Q = qkv + (size_t)(0 * Bn + b) * Nn * Cn;
  const unsigned short* K = qkv + (size_t)(1 * Bn + b) * Nn * Cn;
  const unsigned short* V = qkv + (size_t)(2 * Bn + b) * Nn * Cn;
  const int q0 = qt * 64 + wave * 16;

  short8 qf[8];
  {
    const unsigned short* qp = Q + (size_t)(q0 + l15) * Cn + l4 * 8;
    #pragma unroll
    for (int kk = 0; kk < 8; kk++) qf[kk] = *(const short8*)(qp + kk * 32);
  }
  f32x4 acc_o[16];
  #pragma unroll
  for (int i = 0; i < 16; i++) acc_o[i] = (f32x4){0.f, 0.f, 0.f, 0.f};
  float m_r[4], l_r[4];
  #pragma unroll
  for (int i = 0; i < 4; i++) { m_r[i] = -1e30f; l_r[i] = 0.f; }

  const int kvbase = sp * (Nn / SPLIT);
  const float scl = 0.0625f;                  // 1/sqrt(256)

  for (int step = 0; step < NSTEP; step++) {
    int kv0 = kvbase + step * KVB;
    { // stage K: 64 rows, 4 threads/row, contiguous 128B (8 x uint4) each
      int r = tid >> 2, cp = tid & 3;
      const unsigned short* src = K + (size_t)(kv0 + r) * Cn + cp * 64;
      uint4* dst = (uint4*)&Ks[r][cp * 64];
      #pragma unroll
      for (int i = 0; i < 8; i++) dst[i] = ((const uint4*)src)[i];
    }
    { // stage V transposed: 2 k-rows x 32 ch per thread, packed b32 writes
      int rp = (tid & 31) * 2, ch = (tid >> 5) * 32;
      const unsigned short* s0p = V + (size_t)(kv0 + rp) * Cn + ch;
      const unsigned short* s1p = s0p + Cn;
      union { uint4 v[4]; unsigned short u[32]; } r0, r1;
      #pragma unroll
      for (int i = 0; i < 4; i++) {
        r0.v[i] = ((const uint4*)s0p)[i];
        r1.v[i] = ((const uint4*)s1p)[i];
      }
      #pragma unroll
      for (int j = 0; j < 32; j++) {
        unsigned int pack = (unsigned int)r0.u[j] | ((unsigned int)r1.u[j] << 16);
        *(unsigned int*)&Vt[ch + j][rp] = pack;
      }
    }
    __syncthreads();

    // S = Q K^T over four 16-col tiles
    f32x4 s[4];
    #pragma unroll
    for (int t = 0; t < 4; t++) s[t] = (f32x4){0.f, 0.f, 0.f, 0.f};
    #pragma unroll
    for (int kk = 0; kk < 8; kk++) {
      #pragma unroll
      for (int t = 0; t < 4; t++) {
        short8 bt = *(const short8*)&Ks[t * 16 + l15][kk * 32 + l4 * 8];
        s[t] = mfma16(qf[kk], bt, s[t]);
      }
    }

    // online softmax (rows = l4*4+i, 64 cols = 4 subtiles x 16 lanes)
    float p[4][4], al[4];
    #pragma unroll
    for (int i = 0; i < 4; i++) {
      float a0 = s[0][i] * scl, a1 = s[1][i] * scl;
      float a2 = s[2][i] * scl, a3 = s[3][i] * scl;
      float mt = fmaxf(fmaxf(a0, a1), fmaxf(a2, a3));
      mt = fmaxf(mt, __shfl_xor(mt, 1));
      mt = fmaxf(mt, __shfl_xor(mt, 2));
      mt = fmaxf(mt, __shfl_xor(mt, 4));
      mt = fmaxf(mt, __shfl_xor(mt, 8));
      float mn = fmaxf(m_r[i], mt);
      float a = __expf(m_r[i] - mn);
      m_r[i] = mn; al[i] = a;
      p[0][i] = __expf(a0 - mn);
      p[1][i] = __expf(a1 - mn);
      p[2][i] = __expf(a2 - mn);
      p[3][i] = __expf(a3 - mn);
      float r = (p[0][i] + p[1][i]) + (p[2][i] + p[3][i]);
      r += __shfl_xor(r, 1); r += __shfl_xor(r, 2);
      r += __shfl_xor(r, 4); r += __shfl_xor(r, 8);
      l_r[i] = l_r[i] * a + r;
    }
    // P -> LDS (bf16) in A-fragment layout
    #pragma unroll
    for (int i = 0; i < 4; i++) {
      int row = l4 * 4 + i;
      #pragma unroll
      for (int t = 0; t < 4; t++)
        Pl[wave][row][t * 16 + l15] = f2bf(p[t][i]);
    }
    // rescale O
    #pragma unroll
    for (int ct = 0; ct < 16; ct++)
      #pragma unroll
      for (int i = 0; i < 4; i++) acc_o[ct][i] *= al[i];

    // PV over two K=32 slices
    short8 pf0 = *(const short8*)&Pl[wave][l15][l4 * 8];
    short8 pf1 = *(const short8*)&Pl[wave][l15][32 + l4 * 8];
    #pragma unroll
    for (int ct = 0; ct < 16; ct++) {
      short8 vf0 = *(const short8*)&Vt[ct * 16 + l15][l4 * 8];
      short8 vf1 = *(const short8*)&Vt[ct * 16 + l15][32 + l4 * 8];
      acc_o[ct] = mfma16(pf0, vf0, acc_o[ct]);
      acc_o[ct] = mfma16(pf1, vf1, acc_o[ct]);
    }
    __syncthreads();
  }

  // write unnormalized partials (bf16) + (m,l)
  unsigned short* ob = Opart + ((size_t)(sp * Bn + b) * Nn) * Cn;
  #pragma unroll
  for (int ct = 0; ct < 16; ct++) {
    int c = ct * 16 + l15;
    #pragma unroll
    for (int i = 0; i < 4; i++) {
      int nn = q0 + l4 * 4 + i;
      ob[(size_t)nn * Cn + c] = f2bf(acc_o[ct][i]);
    }
  }
  if (l15 == 0) {
    #pragma unroll
    for (int i = 0; i < 4; i++) {
      int nn = q0 + l4 * 4 + i;
      size_t mb = (((size_t)sp * Bn + b) * Nn + nn) * 2;
      ml[mb]     = m_r[i];
      ml[mb + 1] = l_r[i];
    }
  }
}

// ---------------------------------------------------------------------------
// 6) Combine splits + out = gamma*att + xgT (bf16 residual), transposed via
//    LDS.  Write phase remapped for coalescing: each 8-lane group writes 16
//    consecutive n of one c-row (float2) -> 8 x 64B runs per instruction
//    (was: 64 scattered 16B stores per wave).
// ---------------------------------------------------------------------------
__global__ __launch_bounds__(256) void combine_kernel(
    const unsigned short* __restrict__ Opart, const float* __restrict__ ml,
    const unsigned short* __restrict__ xgT, const float* __restrict__ gamma,
    float* __restrict__ out) {
  __shared__ float T[256][17];
  const int tid = threadIdx.x;
  const int n0 = blockIdx.x * 16;
  const int b = blockIdx.y;
  const float g = gamma[0];
  for (int r = 0; r < 16; r++) {
    int n = n0 + r;
    float msp[SPLIT], lsp[SPLIT];
    float mm = -1e30f;
    #pragma unroll
    for (int s = 0; s < SPLIT; s++) {
      size_t mb = (((size_t)s * Bn + b) * Nn + n) * 2;
      msp[s] = ml[mb]; lsp[s] = ml[mb + 1];
      mm = fmaxf(mm, msp[s]);
    }
    float denom = 0.f, w[SPLIT];
    #pragma unroll
    for (int s = 0; s < SPLIT; s++) { w[s] = __expf(msp[s] - mm); denom += w[s] * lsp[s]; }
    float inv = 1.f / denom;
    float acc = 0.f;
    #pragma unroll
    for (int s = 0; s < SPLIT; s++)
      acc += w[s] * bf2f(Opart[(((size_t)s * Bn + b) * Nn + n) * Cn + tid]);
    float res = bf2f(xgT[((size_t)(b * Nn + n)) * Cn + tid]);
    T[tid][r] = g * acc * inv + res;
  }
  __syncthreads();
  { // coalesced write: lane group (tid&7) covers n-range of c = (tid>>3)+32j
    const int cg = tid >> 3;
    const int nl = (tid & 7) * 2;
    #pragma unroll
    for (int j = 0; j < 8; j++) {
      int c = cg + j * 32;
      float2 v;
      v.x = T[c][nl];
      v.y = T[c][nl + 1];
      *(float2*)(out + ((size_t)(b * Cn + c)) * Nn + n0 + nl) = v;
    }
  }
}

// ---------------------------------------------------------------------------
extern "C" void kernel_launch(void* const* d_in, const int* in_sizes, int n_in,
                              void* d_out, int out_size, void* d_ws, size_t ws_size,
                              hipStream_t stream) {
  const float* x   = (const float*)d_in[0];
  const float* w1  = (const float*)d_in[1];
  const float* b1  = (const float*)d_in[2];
  const float* w2i = (const float*)d_in[3];
  const float* b2  = (const float*)d_in[4];
  const float* w3  = (const float*)d_in[5];
  const float* b3  = (const float*)d_in[6];
  const float* w4  = (const float*)d_in[7];
  const float* b4  = (const float*)d_in[8];
  const float* wq  = (const float*)d_in[9];
  const float* bq  = (const float*)d_in[10];
  const float* wk  = (const float*)d_in[11];
  const float* bk  = (const float*)d_in[12];
  const float* wv  = (const float*)d_in[13];
  const float* bv  = (const float*)d_in[14];
  const float* qs  = (const float*)d_in[15];
  const float* qb  = (const float*)d_in[16];
  const float* ks  = (const float*)d_in[17];
  const float* kb  = (const float*)d_in[18];
  const float* vs  = (const float*)d_in[19];
  const float* vb  = (const float*)d_in[20];
  const float* gamma = (const float*)d_in[21];
  float* out = (float*)d_out;

  char* ws = (char*)d_ws;
  unsigned short* xgT   = (unsigned short*)(ws + 0);         //  4.19 MB
  unsigned short* w2b   = (unsigned short*)(ws + 4194304);   //  1.18 MB
  unsigned short* qkv   = (unsigned short*)(ws + 5373952);   // 12.58 MB
  unsigned short* Opart = (unsigned short*)(ws + 17956864);  // 16.78 MB (bf16, SPLIT=4)
  float* ml             = (float*)(ws + 34734080);           //  0.26 MB (end 35.0MB)

  gated_prepw_kernel<<<dim3(2816), dim3(256), 0, stream>>>(
      x, w1, b1, w2i, b2, w3, b3, w4, b4, wq, wk, wv, xgT, w2b);
  qkvconv_ln_kernel<<<dim3(128, 2, 3), dim3(128), 0, stream>>>(
      xgT, w2b, bq, bk, bv, qs, qb, ks, kb, vs, vb, qkv);
  flash_kernel<<<dim3(64, 2, SPLIT), dim3(256), 0, stream>>>(qkv, Opart, ml);
  combine_kernel<<<dim3(256, 2), dim3(256), 0, stream>>>(Opart, ml, xgT, gamma, out);
}